// Round 1
// baseline (511.161 us; speedup 1.0000x reference)
//
#include <hip/hip_runtime.h>
#include <hip/hip_bf16.h>
#include <math.h>

#define NN 100000
#define EE 1600000
#define FIN 256
#define HID 64
#define NC 40
#define NB 196        // destination buckets of 512 nodes (196*512 = 100352)
#define BCAP 10240    // staging capacity per bucket (mean 8192, +22 sigma)
#define CHUNK 2048    // edges per bucket_kernel block
#define NBKB ((EE + CHUNK - 1) / CHUNK)   // 782

typedef unsigned long long ull;

// ---- stage edges into destination buckets; also accumulate degree sums ----
__global__ __launch_bounds__(256) void bucket_kernel(const int* __restrict__ row,
                                                     const int* __restrict__ col,
                                                     const float* __restrict__ w,
                                                     int* __restrict__ bucket_cnt,
                                                     float* __restrict__ dsum,
                                                     int2* __restrict__ staging) {
    __shared__ int scol[CHUNK];
    __shared__ int2 spay[CHUNK];
    __shared__ int lcnt[NB], lstart[NB];
    const int tid = threadIdx.x;
    const int e0 = blockIdx.x * CHUNK;
    const int nE = min(CHUNK, EE - e0);
    for (int i = tid; i < nE; i += 256) {
        int e = e0 + i;
        int c = col[e];
        float we = w[e];
        scol[i] = c;
        spay[i] = make_int2(((c & 511) << 17) | row[e], __float_as_int(we));
        atomicAdd(&dsum[c], we);          // device-scope; 100k addresses -> low contention
    }
    for (int i = tid; i < NB; i += 256) lcnt[i] = 0;
    __syncthreads();
    for (int i = tid; i < nE; i += 256) atomicAdd(&lcnt[scol[i] >> 9], 1);
    __syncthreads();
    for (int i = tid; i < NB; i += 256) {
        int c = lcnt[i];
        lstart[i] = c ? atomicAdd(&bucket_cnt[i], c) : 0;
        lcnt[i] = 0;
    }
    __syncthreads();
    for (int i = tid; i < nE; i += 256) {
        int b = scol[i] >> 9;
        int slot = lstart[b] + atomicAdd(&lcnt[b], 1);
        if (slot < BCAP) staging[(size_t)b * BCAP + slot] = spay[i];
    }
}

// ---- exclusive scan of bucket counts (one block) ----
__global__ __launch_bounds__(256) void bscan_kernel(int* __restrict__ bucket_cnt,
                                                    int* __restrict__ bucket_base) {
    __shared__ int sd[256];
    int t = threadIdx.x;
    int v = (t < NB) ? min(bucket_cnt[t], BCAP) : 0;
    sd[t] = v;
    __syncthreads();
    for (int off = 1; off < 256; off <<= 1) {
        int u = (t >= off) ? sd[t - off] : 0;
        __syncthreads();
        sd[t] += u;
        __syncthreads();
    }
    if (t < NB) { bucket_base[t] = sd[t] - v; bucket_cnt[t] = v; }
}

// ---- dsum -> dis = rsqrt(deg+1), in place (self-loop weight 1) ----
__global__ __launch_bounds__(256) void dis_kernel(float* __restrict__ dis) {
    int i = blockIdx.x * 256 + threadIdx.x;
    if (i < NN) dis[i] = rsqrtf(dis[i] + 1.0f);
}

// ---- per-bucket: count per dest (LDS), scan, place edges with NORMALIZED weight ----
__global__ __launch_bounds__(512) void build_kernel(const int2* __restrict__ staging,
                                                    const int* __restrict__ bucket_cnt,
                                                    const int* __restrict__ bucket_base,
                                                    const float* __restrict__ dis,
                                                    int2* __restrict__ eme,
                                                    int* __restrict__ basev,
                                                    int* __restrict__ endv) {
    __shared__ int dcnt[512];
    __shared__ int dcur[512];
    __shared__ int sscan[512];
    __shared__ float sdis[512];
    const int t = threadIdx.x;
    const int b = blockIdx.x;
    const int nE = bucket_cnt[b];
    const int ebase = bucket_base[b];
    const int2* st = staging + (size_t)b * BCAP;
    const int gd = b * 512 + t;
    dcnt[t] = 0;
    sdis[t] = (gd < NN) ? dis[gd] : 0.f;
    __syncthreads();
    for (int i = t; i < nE; i += 512) {
        int2 p = st[i];
        atomicAdd(&dcnt[p.x >> 17], 1);
    }
    __syncthreads();
    int c = dcnt[t];
    sscan[t] = c;
    __syncthreads();
    for (int off = 1; off < 512; off <<= 1) {
        int u = (t >= off) ? sscan[t - off] : 0;
        __syncthreads();
        sscan[t] += u;
        __syncthreads();
    }
    int gb = ebase + sscan[t] - c;   // exclusive prefix
    if (gd < NN) { basev[gd] = gb; endv[gd] = gb + c; }
    dcur[t] = gb;
    __syncthreads();
    for (int i = t; i < nE; i += 512) {
        int2 p = st[i];
        int d = p.x >> 17;
        int src = p.x & 0x1FFFF;
        int pos = atomicAdd(&dcur[d], 1);
        float wn = __int_as_float(p.y) * dis[src] * sdis[d];   // dis table is L2-resident
        eme[pos] = make_int2(src, __float_as_int(wn));
    }
}

// ---- GEMM1: xw[N,64](bf16) = x[N,256] @ W1[256,64] ----
__global__ __launch_bounds__(256) void gemm1_kernel(const float* __restrict__ x,
                                                    const float* __restrict__ W,
                                                    __hip_bfloat16* __restrict__ xw) {
    __shared__ float xs[64][65];
    __shared__ float Ws[64][72];
    const int tid = threadIdx.x;
    const int base = blockIdx.x * 64;
    const int ty = tid >> 4;
    const int tx = tid & 15;
    float acc[4][4] = {};

    for (int kb = 0; kb < FIN; kb += 64) {
        for (int v = tid; v < 1024; v += 256) {
            int r = v >> 4, q = v & 15;
            int gr = base + r;
            float4 xv = make_float4(0.f, 0.f, 0.f, 0.f);
            if (gr < NN) xv = *(const float4*)(x + (size_t)gr * FIN + kb + q * 4);
            xs[r][q * 4 + 0] = xv.x; xs[r][q * 4 + 1] = xv.y;
            xs[r][q * 4 + 2] = xv.z; xs[r][q * 4 + 3] = xv.w;
        }
        for (int v = tid; v < 1024; v += 256) {
            int k = v >> 4, q = v & 15;
            float4 wv = *(const float4*)(W + (size_t)(kb + k) * HID + q * 4);
            *(float4*)(&Ws[k][q * 4]) = wv;
        }
        __syncthreads();
#pragma unroll 8
        for (int k = 0; k < 64; k++) {
            float4 wv = *(const float4*)(&Ws[k][tx * 4]);
            float x0 = xs[ty * 4 + 0][k];
            float x1 = xs[ty * 4 + 1][k];
            float x2 = xs[ty * 4 + 2][k];
            float x3 = xs[ty * 4 + 3][k];
            acc[0][0] += x0 * wv.x; acc[0][1] += x0 * wv.y; acc[0][2] += x0 * wv.z; acc[0][3] += x0 * wv.w;
            acc[1][0] += x1 * wv.x; acc[1][1] += x1 * wv.y; acc[1][2] += x1 * wv.z; acc[1][3] += x1 * wv.w;
            acc[2][0] += x2 * wv.x; acc[2][1] += x2 * wv.y; acc[2][2] += x2 * wv.z; acc[2][3] += x2 * wv.w;
            acc[3][0] += x3 * wv.x; acc[3][1] += x3 * wv.y; acc[3][2] += x3 * wv.z; acc[3][3] += x3 * wv.w;
        }
        __syncthreads();
    }
#pragma unroll
    for (int i = 0; i < 4; i++) {
        int gr = base + ty * 4 + i;
        if (gr < NN) {
            union { __hip_bfloat16 h[4]; uint2 u; } pkd;
            pkd.h[0] = __float2bfloat16(acc[i][0]);
            pkd.h[1] = __float2bfloat16(acc[i][1]);
            pkd.h[2] = __float2bfloat16(acc[i][2]);
            pkd.h[3] = __float2bfloat16(acc[i][3]);
            *(uint2*)(xw + (size_t)gr * HID + tx * 4) = pkd.u;
        }
    }
}

// ---- gather1: h[n,f] = relu(sum w'*xw[r,f] + dis^2*xw[n,f] + b1[f]) ----
__global__ __launch_bounds__(256) void gather1_kernel(const int* __restrict__ basev,
                                                      const int* __restrict__ endv,
                                                      const ull* __restrict__ eme,
                                                      const __hip_bfloat16* __restrict__ xw,
                                                      const float* __restrict__ dis,
                                                      const float* __restrict__ b,
                                                      float* __restrict__ h) {
    int n = blockIdx.x * 4 + (threadIdx.x >> 6);
    if (n >= NN) return;
    int lane = threadIdx.x & 63;
    int s = basev[n], t = endv[n];
    float acc = 0.f;
    int p = s;
    for (; p + 16 <= t; p += 16) {
        ull q[16];
#pragma unroll
        for (int j = 0; j < 16; j++) q[j] = __builtin_nontemporal_load(&eme[p + j]);
        float v[16];
#pragma unroll
        for (int j = 0; j < 16; j++) {
            unsigned src = (unsigned)q[j] & 0x1FFFFu;
            v[j] = __bfloat162float(xw[(src << 6) | lane]);
        }
#pragma unroll
        for (int j = 0; j < 16; j++)
            acc += __int_as_float((int)(q[j] >> 32)) * v[j];
    }
    for (; p + 8 <= t; p += 8) {
        ull q[8];
#pragma unroll
        for (int j = 0; j < 8; j++) q[j] = __builtin_nontemporal_load(&eme[p + j]);
        float v[8];
#pragma unroll
        for (int j = 0; j < 8; j++) {
            unsigned src = (unsigned)q[j] & 0x1FFFFu;
            v[j] = __bfloat162float(xw[(src << 6) | lane]);
        }
#pragma unroll
        for (int j = 0; j < 8; j++)
            acc += __int_as_float((int)(q[j] >> 32)) * v[j];
    }
    for (; p + 4 <= t; p += 4) {
        ull q[4];
#pragma unroll
        for (int j = 0; j < 4; j++) q[j] = __builtin_nontemporal_load(&eme[p + j]);
#pragma unroll
        for (int j = 0; j < 4; j++) {
            unsigned src = (unsigned)q[j] & 0x1FFFFu;
            acc += __int_as_float((int)(q[j] >> 32)) *
                   __bfloat162float(xw[(src << 6) | lane]);
        }
    }
    for (; p < t; ++p) {
        ull q = __builtin_nontemporal_load(&eme[p]);
        unsigned src = (unsigned)q & 0x1FFFFu;
        acc += __int_as_float((int)(q >> 32)) *
               __bfloat162float(xw[(src << 6) | lane]);
    }
    float d = dis[n];
    float v = acc + d * d * __bfloat162float(xw[((unsigned)n << 6) | lane]) + b[lane];
    h[(size_t)n * HID + lane] = fmaxf(v, 0.f);
}

// ---- GEMM2: hw2[N,64-padded](bf16) = h[N,64] @ W2[64,40]; rows padded to one 128B line ----
__global__ __launch_bounds__(256) void gemm2_kernel(const float* __restrict__ h,
                                                    const float* __restrict__ W,
                                                    __hip_bfloat16* __restrict__ hw) {
    __shared__ float hs[64][65];
    __shared__ float Ws[HID * NC];
    const int tid = threadIdx.x;
    const int base = blockIdx.x * 64;
    for (int v = tid; v < 1024; v += 256) {
        int r = v >> 4, q = v & 15;
        int gr = base + r;
        float4 hv = make_float4(0.f, 0.f, 0.f, 0.f);
        if (gr < NN) hv = *(const float4*)(h + (size_t)gr * HID + q * 4);
        hs[r][q * 4 + 0] = hv.x; hs[r][q * 4 + 1] = hv.y;
        hs[r][q * 4 + 2] = hv.z; hs[r][q * 4 + 3] = hv.w;
    }
    for (int v = tid; v < HID * NC; v += 256) Ws[v] = W[v];
    __syncthreads();
    const int tx = tid & 7;
    const int ty = tid >> 3;
    float acc[2][5] = {};
#pragma unroll 8
    for (int k = 0; k < HID; k++) {
        float h0 = hs[ty * 2 + 0][k];
        float h1 = hs[ty * 2 + 1][k];
        const float* wr = &Ws[k * NC + tx * 5];
        float w0 = wr[0], w1 = wr[1], w2 = wr[2], w3 = wr[3], w4 = wr[4];
        acc[0][0] += h0 * w0; acc[0][1] += h0 * w1; acc[0][2] += h0 * w2;
        acc[0][3] += h0 * w3; acc[0][4] += h0 * w4;
        acc[1][0] += h1 * w0; acc[1][1] += h1 * w1; acc[1][2] += h1 * w2;
        acc[1][3] += h1 * w3; acc[1][4] += h1 * w4;
    }
#pragma unroll
    for (int i = 0; i < 2; i++) {
        int gr = base + ty * 2 + i;
        if (gr < NN) {
#pragma unroll
            for (int c = 0; c < 5; c++)
                hw[(size_t)gr * 64 + tx * 5 + c] = __float2bfloat16(acc[i][c]);
        }
    }
}

// ---- gather2 + final: out = agg + dis^2*hw + b2 ; log_softmax fused ----
// hw rows are padded to stride 64 (one aligned 128B line); lanes >= NC read
// padding garbage whose accumulator is never used.
__global__ __launch_bounds__(256) void gather2_kernel(const int* __restrict__ basev,
                                                      const int* __restrict__ endv,
                                                      const ull* __restrict__ eme,
                                                      const __hip_bfloat16* __restrict__ hw,
                                                      const float* __restrict__ dis,
                                                      const float* __restrict__ b,
                                                      float* __restrict__ out) {
    int n = blockIdx.x * 4 + (threadIdx.x >> 6);
    if (n >= NN) return;
    int lane = threadIdx.x & 63;
    bool act = lane < NC;
    int s = basev[n], t = endv[n];
    float acc = 0.f;
    int p = s;
    for (; p + 16 <= t; p += 16) {
        ull q[16];
#pragma unroll
        for (int j = 0; j < 16; j++) q[j] = __builtin_nontemporal_load(&eme[p + j]);
        float v[16];
#pragma unroll
        for (int j = 0; j < 16; j++) {
            unsigned src = (unsigned)q[j] & 0x1FFFFu;
            v[j] = __bfloat162float(hw[(src << 6) | lane]);
        }
#pragma unroll
        for (int j = 0; j < 16; j++)
            acc += __int_as_float((int)(q[j] >> 32)) * v[j];
    }
    for (; p + 8 <= t; p += 8) {
        ull q[8];
#pragma unroll
        for (int j = 0; j < 8; j++) q[j] = __builtin_nontemporal_load(&eme[p + j]);
        float v[8];
#pragma unroll
        for (int j = 0; j < 8; j++) {
            unsigned src = (unsigned)q[j] & 0x1FFFFu;
            v[j] = __bfloat162float(hw[(src << 6) | lane]);
        }
#pragma unroll
        for (int j = 0; j < 8; j++)
            acc += __int_as_float((int)(q[j] >> 32)) * v[j];
    }
    for (; p + 4 <= t; p += 4) {
        ull q[4];
#pragma unroll
        for (int j = 0; j < 4; j++) q[j] = __builtin_nontemporal_load(&eme[p + j]);
#pragma unroll
        for (int j = 0; j < 4; j++) {
            unsigned src = (unsigned)q[j] & 0x1FFFFu;
            acc += __int_as_float((int)(q[j] >> 32)) *
                   __bfloat162float(hw[(src << 6) | lane]);
        }
    }
    for (; p < t; ++p) {
        ull q = __builtin_nontemporal_load(&eme[p]);
        unsigned src = (unsigned)q & 0x1FFFFu;
        acc += __int_as_float((int)(q >> 32)) *
               __bfloat162float(hw[(src << 6) | lane]);
    }
    float val = 0.f, v = -INFINITY;
    if (act) {
        float d = dis[n];
        val = acc + d * d * __bfloat162float(hw[((unsigned)n << 6) | lane]) + b[lane];
        v = val;
    }
    float m = v;
#pragma unroll
    for (int off = 32; off; off >>= 1) m = fmaxf(m, __shfl_xor(m, off));
    float e = act ? expf(val - m) : 0.f;
    float sum = e;
#pragma unroll
    for (int off = 32; off; off >>= 1) sum += __shfl_xor(sum, off);
    float lse = m + logf(sum);
    if (act) {
        size_t idx = (size_t)n * NC + lane;
        out[idx] = val;
        out[(size_t)NN * NC + idx] = val - lse;
    }
}

extern "C" void kernel_launch(void* const* d_in, const int* in_sizes, int n_in,
                              void* d_out, int out_size, void* d_ws, size_t ws_size,
                              hipStream_t stream) {
    const float* x    = (const float*)d_in[0];
    const int*   eidx = (const int*)d_in[1];
    const float* ew   = (const float*)d_in[2];
    const float* W1   = (const float*)d_in[3];
    const float* b1   = (const float*)d_in[4];
    const float* W2   = (const float*)d_in[5];
    const float* b2   = (const float*)d_in[6];
    float* out = (float*)d_out;

    const int* row = eidx;
    const int* col = eidx + EE;

    char* ws = (char*)d_ws;
    int*   bucket_cnt  = (int*)ws;               ws += 256 * 4;
    float* dis    = (float*)ws;                  ws += NN * 4;   // dsum accumulator, then rsqrt in place
    int*   bucket_base = (int*)ws;               ws += 256 * 4;
    int*   basev  = (int*)ws;                    ws += NN * 4;
    int*   endv   = (int*)ws;                    ws += NN * 4;
    int2*  eme    = (int2*)ws;                   ws += (size_t)EE * 8;
    __hip_bfloat16* xw = (__hip_bfloat16*)ws;    ws += (size_t)NN * HID * 2;
    // staging (16.06 MB) and h (25.6 MB) are never live simultaneously: union them
    char* unionp = ws;                           ws += (size_t)NN * HID * 4;
    int2*  staging = (int2*)unionp;              // NB*BCAP*8 = 16.06 MB <= 25.6 MB
    float* h       = (float*)unionp;
    __hip_bfloat16* hw2 = (__hip_bfloat16*)ws;   ws += (size_t)NN * 64 * 2;  // stride-64 padded

    // one memset covers bucket_cnt (1 KB) + dis/dsum (400 KB): contiguous
    hipMemsetAsync(bucket_cnt, 0, 256 * 4 + NN * 4, stream);

    bucket_kernel<<<NBKB, 256, 0, stream>>>(row, col, ew, bucket_cnt, dis, staging);
    bscan_kernel<<<1, 256, 0, stream>>>(bucket_cnt, bucket_base);
    dis_kernel<<<(NN + 255) / 256, 256, 0, stream>>>(dis);
    build_kernel<<<NB, 512, 0, stream>>>(staging, bucket_cnt, bucket_base, dis,
                                         eme, basev, endv);
    gemm1_kernel<<<(NN + 63) / 64, 256, 0, stream>>>(x, W1, xw);
    gather1_kernel<<<(NN + 3) / 4, 256, 0, stream>>>(basev, endv, (const ull*)eme,
                                                     xw, dis, b1, h);
    gemm2_kernel<<<(NN + 63) / 64, 256, 0, stream>>>(h, W2, hw2);
    gather2_kernel<<<(NN + 3) / 4, 256, 0, stream>>>(basev, endv, (const ull*)eme,
                                                     hw2, dis, b2, out);
}

// Round 3
// 441.969 us; speedup vs baseline: 1.1566x; 1.1566x over previous
//
#include <hip/hip_runtime.h>
#include <hip/hip_bf16.h>
#include <math.h>

#define NN 100000
#define EE 1600000
#define FIN 256
#define HID 64
#define NC 40
#define NB 196        // destination buckets of 512 nodes (196*512 = 100352)
#define BCAP 10240    // staging capacity per bucket (mean 8192, +22 sigma)
#define CHUNK 2048    // edges per bucket_kernel block
#define NBKB ((EE + CHUNK - 1) / CHUNK)   // 782

typedef unsigned long long ull;

// ---- stage edges into destination buckets; LDS-reorder by bucket for coalesced writes ----
__global__ __launch_bounds__(256) void bucket_kernel(const int* __restrict__ row,
                                                     const int* __restrict__ col,
                                                     const float* __restrict__ w,
                                                     int* __restrict__ bucket_cnt,
                                                     int2* __restrict__ staging) {
    __shared__ int2 spay[CHUNK];            // 16 KB  original-order payload
    __shared__ int2 sorted[CHUNK];          // 16 KB  bucket-ordered payload
    __shared__ unsigned char sb[CHUNK];     // 2 KB   bucket id per original slot
    __shared__ unsigned char sbk[CHUNK];    // 2 KB   bucket id per sorted slot
    __shared__ int lcnt[NB], lofs[NB], lstart[NB];
    __shared__ int sscan[256];
    const int tid = threadIdx.x;
    const int e0 = blockIdx.x * CHUNK;
    const int nE = min(CHUNK, EE - e0);
    for (int i = tid; i < nE; i += 256) {
        int e = e0 + i;
        int c = col[e];
        sb[i] = (unsigned char)(c >> 9);
        spay[i] = make_int2(((c & 511) << 17) | row[e], __float_as_int(w[e]));
    }
    for (int i = tid; i < NB; i += 256) lcnt[i] = 0;
    __syncthreads();
    for (int i = tid; i < nE; i += 256) atomicAdd(&lcnt[sb[i]], 1);
    __syncthreads();
    // exclusive scan of lcnt over NB (<=256)
    int v = (tid < NB) ? lcnt[tid] : 0;
    sscan[tid] = v;
    __syncthreads();
    for (int off = 1; off < 256; off <<= 1) {
        int u = (tid >= off) ? sscan[tid - off] : 0;
        __syncthreads();
        sscan[tid] += u;
        __syncthreads();
    }
    if (tid < NB) {
        lofs[tid] = sscan[tid] - v;                       // local exclusive prefix
        lstart[tid] = v ? atomicAdd(&bucket_cnt[tid], v) : 0;  // global base for this block's run
        lcnt[tid] = 0;
    }
    __syncthreads();
    // reorder into bucket-contiguous LDS
    for (int i = tid; i < nE; i += 256) {
        int b = sb[i];
        int p = lofs[b] + atomicAdd(&lcnt[b], 1);
        sorted[p] = spay[i];
        sbk[p] = (unsigned char)b;
    }
    __syncthreads();
    // write out: consecutive threads -> consecutive slots of the same bucket
    for (int p = tid; p < nE; p += 256) {
        int b = sbk[p];
        int slot = lstart[b] + (p - lofs[b]);
        if (slot < BCAP) staging[(size_t)b * BCAP + slot] = sorted[p];
    }
}

// ---- exclusive scan of bucket counts (one block) ----
__global__ __launch_bounds__(256) void bscan_kernel(int* __restrict__ bucket_cnt,
                                                    int* __restrict__ bucket_base) {
    __shared__ int sd[256];
    int t = threadIdx.x;
    int v = (t < NB) ? min(bucket_cnt[t], BCAP) : 0;
    sd[t] = v;
    __syncthreads();
    for (int off = 1; off < 256; off <<= 1) {
        int u = (t >= off) ? sd[t - off] : 0;
        __syncthreads();
        sd[t] += u;
        __syncthreads();
    }
    if (t < NB) { bucket_base[t] = sd[t] - v; bucket_cnt[t] = v; }
}

// ---- build pass A: per-dest count + weighted degree (LDS atomics), scan, basev/endv, dis ----
__global__ __launch_bounds__(512) void build_count_kernel(const int2* __restrict__ staging,
                                                          const int* __restrict__ bucket_cnt,
                                                          const int* __restrict__ bucket_base,
                                                          int* __restrict__ basev,
                                                          int* __restrict__ endv,
                                                          float* __restrict__ dis) {
    __shared__ int dcnt[512];
    __shared__ float dsum[512];
    __shared__ int sscan[512];
    const int t = threadIdx.x;
    const int b = blockIdx.x;
    const int nE = bucket_cnt[b];
    const int ebase = bucket_base[b];
    const int2* st = staging + (size_t)b * BCAP;
    dcnt[t] = 0; dsum[t] = 0.f;
    __syncthreads();
    for (int i = t; i < nE; i += 512) {
        int2 p = st[i];
        int d = p.x >> 17;
        atomicAdd(&dcnt[d], 1);
        atomicAdd(&dsum[d], __int_as_float(p.y));
    }
    __syncthreads();
    int c = dcnt[t];
    sscan[t] = c;
    __syncthreads();
    for (int off = 1; off < 512; off <<= 1) {
        int u = (t >= off) ? sscan[t - off] : 0;
        __syncthreads();
        sscan[t] += u;
        __syncthreads();
    }
    int gb = ebase + sscan[t] - c;   // exclusive prefix
    int gd = b * 512 + t;
    if (gd < NN) {
        basev[gd] = gb;
        endv[gd] = gb + c;
        dis[gd] = rsqrtf(dsum[t] + 1.0f);   // self-loop weight 1
    }
}

// ---- build pass B: place edges with fully-normalized weight (dis complete, L2-resident) ----
__global__ __launch_bounds__(512) void build_place_kernel(const int2* __restrict__ staging,
                                                          const int* __restrict__ bucket_cnt,
                                                          const int* __restrict__ basev,
                                                          const float* __restrict__ dis,
                                                          int2* __restrict__ eme) {
    __shared__ int dcur[512];
    __shared__ float sdis[512];
    const int t = threadIdx.x;
    const int b = blockIdx.x;
    const int nE = bucket_cnt[b];
    const int2* st = staging + (size_t)b * BCAP;
    const int gd = b * 512 + t;
    dcur[t] = (gd < NN) ? basev[gd] : 0;
    sdis[t] = (gd < NN) ? dis[gd] : 0.f;
    __syncthreads();
    for (int i = t; i < nE; i += 512) {
        int2 p = st[i];
        int d = p.x >> 17;
        int src = p.x & 0x1FFFF;
        int pos = atomicAdd(&dcur[d], 1);
        float wn = __int_as_float(p.y) * dis[src] * sdis[d];
        eme[pos] = make_int2(src, __float_as_int(wn));
    }
}

// ---- GEMM1: xw[N,64](bf16) = x[N,256] @ W1[256,64] ----
__global__ __launch_bounds__(256) void gemm1_kernel(const float* __restrict__ x,
                                                    const float* __restrict__ W,
                                                    __hip_bfloat16* __restrict__ xw) {
    __shared__ float xs[64][65];
    __shared__ float Ws[64][72];
    const int tid = threadIdx.x;
    const int base = blockIdx.x * 64;
    const int ty = tid >> 4;
    const int tx = tid & 15;
    float acc[4][4] = {};

    for (int kb = 0; kb < FIN; kb += 64) {
        for (int v = tid; v < 1024; v += 256) {
            int r = v >> 4, q = v & 15;
            int gr = base + r;
            float4 xv = make_float4(0.f, 0.f, 0.f, 0.f);
            if (gr < NN) xv = *(const float4*)(x + (size_t)gr * FIN + kb + q * 4);
            xs[r][q * 4 + 0] = xv.x; xs[r][q * 4 + 1] = xv.y;
            xs[r][q * 4 + 2] = xv.z; xs[r][q * 4 + 3] = xv.w;
        }
        for (int v = tid; v < 1024; v += 256) {
            int k = v >> 4, q = v & 15;
            float4 wv = *(const float4*)(W + (size_t)(kb + k) * HID + q * 4);
            *(float4*)(&Ws[k][q * 4]) = wv;
        }
        __syncthreads();
#pragma unroll 8
        for (int k = 0; k < 64; k++) {
            float4 wv = *(const float4*)(&Ws[k][tx * 4]);
            float x0 = xs[ty * 4 + 0][k];
            float x1 = xs[ty * 4 + 1][k];
            float x2 = xs[ty * 4 + 2][k];
            float x3 = xs[ty * 4 + 3][k];
            acc[0][0] += x0 * wv.x; acc[0][1] += x0 * wv.y; acc[0][2] += x0 * wv.z; acc[0][3] += x0 * wv.w;
            acc[1][0] += x1 * wv.x; acc[1][1] += x1 * wv.y; acc[1][2] += x1 * wv.z; acc[1][3] += x1 * wv.w;
            acc[2][0] += x2 * wv.x; acc[2][1] += x2 * wv.y; acc[2][2] += x2 * wv.z; acc[2][3] += x2 * wv.w;
            acc[3][0] += x3 * wv.x; acc[3][1] += x3 * wv.y; acc[3][2] += x3 * wv.z; acc[3][3] += x3 * wv.w;
        }
        __syncthreads();
    }
#pragma unroll
    for (int i = 0; i < 4; i++) {
        int gr = base + ty * 4 + i;
        if (gr < NN) {
            union { __hip_bfloat16 h[4]; uint2 u; } pkd;
            pkd.h[0] = __float2bfloat16(acc[i][0]);
            pkd.h[1] = __float2bfloat16(acc[i][1]);
            pkd.h[2] = __float2bfloat16(acc[i][2]);
            pkd.h[3] = __float2bfloat16(acc[i][3]);
            *(uint2*)(xw + (size_t)gr * HID + tx * 4) = pkd.u;
        }
    }
}

// ---- gather1: h[n,f] = relu(sum w'*xw[r,f] + dis^2*xw[n,f] + b1[f]) ----
__global__ __launch_bounds__(256) void gather1_kernel(const int* __restrict__ basev,
                                                      const int* __restrict__ endv,
                                                      const ull* __restrict__ eme,
                                                      const __hip_bfloat16* __restrict__ xw,
                                                      const float* __restrict__ dis,
                                                      const float* __restrict__ b,
                                                      float* __restrict__ h) {
    int n = blockIdx.x * 4 + (threadIdx.x >> 6);
    if (n >= NN) return;
    int lane = threadIdx.x & 63;
    int s = basev[n], t = endv[n];
    float acc = 0.f;
    int p = s;
    for (; p + 16 <= t; p += 16) {
        ull q[16];
#pragma unroll
        for (int j = 0; j < 16; j++) q[j] = __builtin_nontemporal_load(&eme[p + j]);
        float v[16];
#pragma unroll
        for (int j = 0; j < 16; j++) {
            unsigned src = (unsigned)q[j] & 0x1FFFFu;
            v[j] = __bfloat162float(xw[(src << 6) | lane]);
        }
#pragma unroll
        for (int j = 0; j < 16; j++)
            acc += __int_as_float((int)(q[j] >> 32)) * v[j];
    }
    for (; p + 8 <= t; p += 8) {
        ull q[8];
#pragma unroll
        for (int j = 0; j < 8; j++) q[j] = __builtin_nontemporal_load(&eme[p + j]);
        float v[8];
#pragma unroll
        for (int j = 0; j < 8; j++) {
            unsigned src = (unsigned)q[j] & 0x1FFFFu;
            v[j] = __bfloat162float(xw[(src << 6) | lane]);
        }
#pragma unroll
        for (int j = 0; j < 8; j++)
            acc += __int_as_float((int)(q[j] >> 32)) * v[j];
    }
    for (; p + 4 <= t; p += 4) {
        ull q[4];
#pragma unroll
        for (int j = 0; j < 4; j++) q[j] = __builtin_nontemporal_load(&eme[p + j]);
#pragma unroll
        for (int j = 0; j < 4; j++) {
            unsigned src = (unsigned)q[j] & 0x1FFFFu;
            acc += __int_as_float((int)(q[j] >> 32)) *
                   __bfloat162float(xw[(src << 6) | lane]);
        }
    }
    for (; p < t; ++p) {
        ull q = __builtin_nontemporal_load(&eme[p]);
        unsigned src = (unsigned)q & 0x1FFFFu;
        acc += __int_as_float((int)(q >> 32)) *
               __bfloat162float(xw[(src << 6) | lane]);
    }
    float d = dis[n];
    float v = acc + d * d * __bfloat162float(xw[((unsigned)n << 6) | lane]) + b[lane];
    h[(size_t)n * HID + lane] = fmaxf(v, 0.f);
}

// ---- GEMM2: hw2[N,64-padded](bf16) = h[N,64] @ W2[64,40]; rows padded to one 128B line ----
__global__ __launch_bounds__(256) void gemm2_kernel(const float* __restrict__ h,
                                                    const float* __restrict__ W,
                                                    __hip_bfloat16* __restrict__ hw) {
    __shared__ float hs[64][65];
    __shared__ float Ws[HID * NC];
    const int tid = threadIdx.x;
    const int base = blockIdx.x * 64;
    for (int v = tid; v < 1024; v += 256) {
        int r = v >> 4, q = v & 15;
        int gr = base + r;
        float4 hv = make_float4(0.f, 0.f, 0.f, 0.f);
        if (gr < NN) hv = *(const float4*)(h + (size_t)gr * HID + q * 4);
        hs[r][q * 4 + 0] = hv.x; hs[r][q * 4 + 1] = hv.y;
        hs[r][q * 4 + 2] = hv.z; hs[r][q * 4 + 3] = hv.w;
    }
    for (int v = tid; v < HID * NC; v += 256) Ws[v] = W[v];
    __syncthreads();
    const int tx = tid & 7;
    const int ty = tid >> 3;
    float acc[2][5] = {};
#pragma unroll 8
    for (int k = 0; k < HID; k++) {
        float h0 = hs[ty * 2 + 0][k];
        float h1 = hs[ty * 2 + 1][k];
        const float* wr = &Ws[k * NC + tx * 5];
        float w0 = wr[0], w1 = wr[1], w2 = wr[2], w3 = wr[3], w4 = wr[4];
        acc[0][0] += h0 * w0; acc[0][1] += h0 * w1; acc[0][2] += h0 * w2;
        acc[0][3] += h0 * w3; acc[0][4] += h0 * w4;
        acc[1][0] += h1 * w0; acc[1][1] += h1 * w1; acc[1][2] += h1 * w2;
        acc[1][3] += h1 * w3; acc[1][4] += h1 * w4;
    }
#pragma unroll
    for (int i = 0; i < 2; i++) {
        int gr = base + ty * 2 + i;
        if (gr < NN) {
#pragma unroll
            for (int c = 0; c < 5; c++)
                hw[(size_t)gr * 64 + tx * 5 + c] = __float2bfloat16(acc[i][c]);
        }
    }
}

// ---- gather2 + final: out = agg + dis^2*hw + b2 ; log_softmax fused ----
// hw rows are padded to stride 64 (one aligned 128B line); lanes >= NC read
// padding garbage whose accumulator is never used.
__global__ __launch_bounds__(256) void gather2_kernel(const int* __restrict__ basev,
                                                      const int* __restrict__ endv,
                                                      const ull* __restrict__ eme,
                                                      const __hip_bfloat16* __restrict__ hw,
                                                      const float* __restrict__ dis,
                                                      const float* __restrict__ b,
                                                      float* __restrict__ out) {
    int n = blockIdx.x * 4 + (threadIdx.x >> 6);
    if (n >= NN) return;
    int lane = threadIdx.x & 63;
    bool act = lane < NC;
    int s = basev[n], t = endv[n];
    float acc = 0.f;
    int p = s;
    for (; p + 16 <= t; p += 16) {
        ull q[16];
#pragma unroll
        for (int j = 0; j < 16; j++) q[j] = __builtin_nontemporal_load(&eme[p + j]);
        float v[16];
#pragma unroll
        for (int j = 0; j < 16; j++) {
            unsigned src = (unsigned)q[j] & 0x1FFFFu;
            v[j] = __bfloat162float(hw[(src << 6) | lane]);
        }
#pragma unroll
        for (int j = 0; j < 16; j++)
            acc += __int_as_float((int)(q[j] >> 32)) * v[j];
    }
    for (; p + 8 <= t; p += 8) {
        ull q[8];
#pragma unroll
        for (int j = 0; j < 8; j++) q[j] = __builtin_nontemporal_load(&eme[p + j]);
        float v[8];
#pragma unroll
        for (int j = 0; j < 8; j++) {
            unsigned src = (unsigned)q[j] & 0x1FFFFu;
            v[j] = __bfloat162float(hw[(src << 6) | lane]);
        }
#pragma unroll
        for (int j = 0; j < 8; j++)
            acc += __int_as_float((int)(q[j] >> 32)) * v[j];
    }
    for (; p + 4 <= t; p += 4) {
        ull q[4];
#pragma unroll
        for (int j = 0; j < 4; j++) q[j] = __builtin_nontemporal_load(&eme[p + j]);
#pragma unroll
        for (int j = 0; j < 4; j++) {
            unsigned src = (unsigned)q[j] & 0x1FFFFu;
            acc += __int_as_float((int)(q[j] >> 32)) *
                   __bfloat162float(hw[(src << 6) | lane]);
        }
    }
    for (; p < t; ++p) {
        ull q = __builtin_nontemporal_load(&eme[p]);
        unsigned src = (unsigned)q & 0x1FFFFu;
        acc += __int_as_float((int)(q >> 32)) *
               __bfloat162float(hw[(src << 6) | lane]);
    }
    float val = 0.f, v = -INFINITY;
    if (act) {
        float d = dis[n];
        val = acc + d * d * __bfloat162float(hw[((unsigned)n << 6) | lane]) + b[lane];
        v = val;
    }
    float m = v;
#pragma unroll
    for (int off = 32; off; off >>= 1) m = fmaxf(m, __shfl_xor(m, off));
    float e = act ? expf(val - m) : 0.f;
    float sum = e;
#pragma unroll
    for (int off = 32; off; off >>= 1) sum += __shfl_xor(sum, off);
    float lse = m + logf(sum);
    if (act) {
        size_t idx = (size_t)n * NC + lane;
        out[idx] = val;
        out[(size_t)NN * NC + idx] = val - lse;
    }
}

extern "C" void kernel_launch(void* const* d_in, const int* in_sizes, int n_in,
                              void* d_out, int out_size, void* d_ws, size_t ws_size,
                              hipStream_t stream) {
    const float* x    = (const float*)d_in[0];
    const int*   eidx = (const int*)d_in[1];
    const float* ew   = (const float*)d_in[2];
    const float* W1   = (const float*)d_in[3];
    const float* b1   = (const float*)d_in[4];
    const float* W2   = (const float*)d_in[5];
    const float* b2   = (const float*)d_in[6];
    float* out = (float*)d_out;

    const int* row = eidx;
    const int* col = eidx + EE;

    char* ws = (char*)d_ws;
    int*   bucket_cnt  = (int*)ws;               ws += 256 * 4;
    int*   bucket_base = (int*)ws;               ws += 256 * 4;
    float* dis    = (float*)ws;                  ws += NN * 4;
    int*   basev  = (int*)ws;                    ws += NN * 4;
    int*   endv   = (int*)ws;                    ws += NN * 4;
    int2*  eme    = (int2*)ws;                   ws += (size_t)EE * 8;
    __hip_bfloat16* xw = (__hip_bfloat16*)ws;    ws += (size_t)NN * HID * 2;
    // staging (16.06 MB) and h (25.6 MB) are never live simultaneously: union them
    char* unionp = ws;                           ws += (size_t)NN * HID * 4;
    int2*  staging = (int2*)unionp;              // NB*BCAP*8 = 16.06 MB <= 25.6 MB
    float* h       = (float*)unionp;
    __hip_bfloat16* hw2 = (__hip_bfloat16*)ws;   ws += (size_t)NN * 64 * 2;  // stride-64 padded

    hipMemsetAsync(bucket_cnt, 0, 256 * 4, stream);

    bucket_kernel<<<NBKB, 256, 0, stream>>>(row, col, ew, bucket_cnt, staging);
    bscan_kernel<<<1, 256, 0, stream>>>(bucket_cnt, bucket_base);
    build_count_kernel<<<NB, 512, 0, stream>>>(staging, bucket_cnt, bucket_base,
                                               basev, endv, dis);
    build_place_kernel<<<NB, 512, 0, stream>>>(staging, bucket_cnt, basev, dis, eme);
    gemm1_kernel<<<(NN + 63) / 64, 256, 0, stream>>>(x, W1, xw);
    gather1_kernel<<<(NN + 3) / 4, 256, 0, stream>>>(basev, endv, (const ull*)eme,
                                                     xw, dis, b1, h);
    gemm2_kernel<<<(NN + 63) / 64, 256, 0, stream>>>(h, W2, hw2);
    gather2_kernel<<<(NN + 3) / 4, 256, 0, stream>>>(basev, endv, (const ull*)eme,
                                                     hw2, dis, b2, out);
}

// Round 4
// 430.250 us; speedup vs baseline: 1.1881x; 1.0272x over previous
//
#include <hip/hip_runtime.h>
#include <hip/hip_bf16.h>
#include <math.h>

#define NN 100000
#define EE 1600000
#define FIN 256
#define HID 64
#define NC 40
#define NB 196        // destination buckets of 512 nodes (196*512 = 100352)
#define BCAP 10240    // staging capacity per bucket (mean 8192, +22 sigma)
#define CHUNK 2048    // edges per bucket_kernel block
#define NBKB ((EE + CHUNK - 1) / CHUNK)   // 782

typedef unsigned long long ull;
typedef __attribute__((ext_vector_type(8))) short short8;
typedef __attribute__((ext_vector_type(4))) float f32x4;

__device__ __forceinline__ unsigned short f2bf_rne(float f) {
    unsigned u = __float_as_uint(f);
    u += 0x7FFFu + ((u >> 16) & 1u);
    return (unsigned short)(u >> 16);
}
__device__ __forceinline__ float bf2f(unsigned short b) {
    return __uint_as_float((unsigned)b << 16);
}

// ---- stage edges into destination buckets; LDS-reorder by bucket for coalesced writes ----
__global__ __launch_bounds__(256) void bucket_kernel(const int* __restrict__ row,
                                                     const int* __restrict__ col,
                                                     const float* __restrict__ w,
                                                     int* __restrict__ bucket_cnt,
                                                     int2* __restrict__ staging) {
    __shared__ int2 spay[CHUNK];            // 16 KB  original-order payload
    __shared__ int2 sorted[CHUNK];          // 16 KB  bucket-ordered payload
    __shared__ unsigned char sb[CHUNK];     // 2 KB   bucket id per original slot
    __shared__ unsigned char sbk[CHUNK];    // 2 KB   bucket id per sorted slot
    __shared__ int lcnt[NB], lofs[NB], lstart[NB];
    __shared__ int sscan[256];
    const int tid = threadIdx.x;
    const int e0 = blockIdx.x * CHUNK;
    const int nE = min(CHUNK, EE - e0);
    for (int i = tid; i < nE; i += 256) {
        int e = e0 + i;
        int c = col[e];
        sb[i] = (unsigned char)(c >> 9);
        spay[i] = make_int2(((c & 511) << 17) | row[e], __float_as_int(w[e]));
    }
    for (int i = tid; i < NB; i += 256) lcnt[i] = 0;
    __syncthreads();
    for (int i = tid; i < nE; i += 256) atomicAdd(&lcnt[sb[i]], 1);
    __syncthreads();
    // exclusive scan of lcnt over NB (<=256)
    int v = (tid < NB) ? lcnt[tid] : 0;
    sscan[tid] = v;
    __syncthreads();
    for (int off = 1; off < 256; off <<= 1) {
        int u = (tid >= off) ? sscan[tid - off] : 0;
        __syncthreads();
        sscan[tid] += u;
        __syncthreads();
    }
    if (tid < NB) {
        lofs[tid] = sscan[tid] - v;                       // local exclusive prefix
        lstart[tid] = v ? atomicAdd(&bucket_cnt[tid], v) : 0;  // global base for this block's run
        lcnt[tid] = 0;
    }
    __syncthreads();
    // reorder into bucket-contiguous LDS
    for (int i = tid; i < nE; i += 256) {
        int b = sb[i];
        int p = lofs[b] + atomicAdd(&lcnt[b], 1);
        sorted[p] = spay[i];
        sbk[p] = (unsigned char)b;
    }
    __syncthreads();
    // write out: consecutive threads -> consecutive slots of the same bucket
    for (int p = tid; p < nE; p += 256) {
        int b = sbk[p];
        int slot = lstart[b] + (p - lofs[b]);
        if (slot < BCAP) staging[(size_t)b * BCAP + slot] = sorted[p];
    }
}

// ---- block 0: exclusive scan of bucket counts; blocks 1..4: W1 -> B^T bf16 hi/lo tables ----
__global__ __launch_bounds__(256) void bscan_w1cvt_kernel(int* __restrict__ bucket_cnt,
                                                          int* __restrict__ bucket_base,
                                                          const float* __restrict__ W1,
                                                          unsigned short* __restrict__ w1hi,
                                                          unsigned short* __restrict__ w1lo) {
    if (blockIdx.x == 0) {
        __shared__ int sd[256];
        int t = threadIdx.x;
        int v = (t < NB) ? min(bucket_cnt[t], BCAP) : 0;
        sd[t] = v;
        __syncthreads();
        for (int off = 1; off < 256; off <<= 1) {
            int u = (t >= off) ? sd[t - off] : 0;
            __syncthreads();
            sd[t] += u;
            __syncthreads();
        }
        if (t < NB) { bucket_base[t] = sd[t] - v; bucket_cnt[t] = v; }
    } else {
        int b = blockIdx.x - 1;          // 0..3
        for (int i = threadIdx.x; i < 4096; i += 256) {
            int e = b * 4096 + i;        // e = c*256 + k  (B^T layout)
            int c = e >> 8, k = e & 255;
            float v = W1[(size_t)k * HID + c];
            unsigned short h = f2bf_rne(v);
            w1hi[e] = h;
            w1lo[e] = f2bf_rne(v - bf2f(h));
        }
    }
}

// ---- build pass A: per-dest count + weighted degree (LDS atomics), scan, basev/endv, dis ----
__global__ __launch_bounds__(512) void build_count_kernel(const int2* __restrict__ staging,
                                                          const int* __restrict__ bucket_cnt,
                                                          const int* __restrict__ bucket_base,
                                                          int* __restrict__ basev,
                                                          int* __restrict__ endv,
                                                          float* __restrict__ dis) {
    __shared__ int dcnt[512];
    __shared__ float dsum[512];
    __shared__ int sscan[512];
    const int t = threadIdx.x;
    const int b = blockIdx.x;
    const int nE = bucket_cnt[b];
    const int ebase = bucket_base[b];
    const int2* st = staging + (size_t)b * BCAP;
    dcnt[t] = 0; dsum[t] = 0.f;
    __syncthreads();
    for (int i = t; i < nE; i += 512) {
        int2 p = st[i];
        int d = p.x >> 17;
        atomicAdd(&dcnt[d], 1);
        atomicAdd(&dsum[d], __int_as_float(p.y));
    }
    __syncthreads();
    int c = dcnt[t];
    sscan[t] = c;
    __syncthreads();
    for (int off = 1; off < 512; off <<= 1) {
        int u = (t >= off) ? sscan[t - off] : 0;
        __syncthreads();
        sscan[t] += u;
        __syncthreads();
    }
    int gb = ebase + sscan[t] - c;   // exclusive prefix
    int gd = b * 512 + t;
    if (gd < NN) {
        basev[gd] = gb;
        endv[gd] = gb + c;
        dis[gd] = rsqrtf(dsum[t] + 1.0f);   // self-loop weight 1
    }
}

// ---- build pass B: place edges with fully-normalized weight (dis complete, L2-resident) ----
__global__ __launch_bounds__(512) void build_place_kernel(const int2* __restrict__ staging,
                                                          const int* __restrict__ bucket_cnt,
                                                          const int* __restrict__ basev,
                                                          const float* __restrict__ dis,
                                                          int2* __restrict__ eme) {
    __shared__ int dcur[512];
    __shared__ float sdis[512];
    const int t = threadIdx.x;
    const int b = blockIdx.x;
    const int nE = bucket_cnt[b];
    const int2* st = staging + (size_t)b * BCAP;
    const int gd = b * 512 + t;
    dcur[t] = (gd < NN) ? basev[gd] : 0;
    sdis[t] = (gd < NN) ? dis[gd] : 0.f;
    __syncthreads();
    for (int i = t; i < nE; i += 512) {
        int2 p = st[i];
        int d = p.x >> 17;
        int src = p.x & 0x1FFFF;
        int pos = atomicAdd(&dcur[d], 1);
        float wn = __int_as_float(p.y) * dis[src] * sdis[d];
        eme[pos] = make_int2(src, __float_as_int(wn));
    }
}

// ---- GEMM1 (MFMA, split-bf16 f32 emulation): xw[N,64](bf16) = x[N,256] @ W1[256,64] ----
// Block = 256 threads = 4 waves; each wave owns 32 rows x 64 cols.
// A loaded direct from global (coalesced 128B rows), converted to bf16 hi/lo in-reg.
// B from preconverted B^T hi/lo tables (L2-resident). No LDS, no barriers.
// hi*hi + hi*lo + lo*hi keeps ~16 mantissa bits (error ~2^-16, below bf16 output rounding).
__global__ __launch_bounds__(256) void gemm1_mfma_kernel(const float* __restrict__ x,
                                                         const unsigned short* __restrict__ w1hi,
                                                         const unsigned short* __restrict__ w1lo,
                                                         __hip_bfloat16* __restrict__ xw) {
    const int tid = threadIdx.x;
    const int wid = tid >> 6;
    const int l   = tid & 63;
    const int r   = l & 15;        // A row within 16-tile / B col within 16-tile
    const int kg  = l >> 4;        // k-group 0..3 (8 contiguous k each)
    const int rb0 = blockIdx.x * 128 + wid * 32;   // wave's first row

    f32x4 acc[2][4];
#pragma unroll
    for (int i = 0; i < 2; i++)
#pragma unroll
        for (int j = 0; j < 4; j++) acc[i][j] = (f32x4){0.f, 0.f, 0.f, 0.f};

    int row0 = rb0 + r;
    int row1 = rb0 + 16 + r;
    int row0c = row0 < NN ? row0 : NN - 1;   // clamp loads; stores are guarded
    int row1c = row1 < NN ? row1 : NN - 1;
    const float* a0p = x + (size_t)row0c * FIN + kg * 8;
    const float* a1p = x + (size_t)row1c * FIN + kg * 8;

#pragma unroll
    for (int ks = 0; ks < 8; ks++) {
        // B fragments for 4 col-tiles: col = ct*16 + r, k in [ks*32 + kg*8, +8)
        short8 bhi[4], blo[4];
#pragma unroll
        for (int ct = 0; ct < 4; ct++) {
            size_t off = (size_t)(ct * 16 + r) * FIN + ks * 32 + kg * 8;
            bhi[ct] = *(const short8*)(w1hi + off);
            blo[ct] = *(const short8*)(w1lo + off);
        }
        // A: 8 contiguous f32 per row-tile
        float4 af0a = *(const float4*)(a0p + ks * 32);
        float4 af0b = *(const float4*)(a0p + ks * 32 + 4);
        float4 af1a = *(const float4*)(a1p + ks * 32);
        float4 af1b = *(const float4*)(a1p + ks * 32 + 4);
        float a0v[8] = {af0a.x, af0a.y, af0a.z, af0a.w, af0b.x, af0b.y, af0b.z, af0b.w};
        float a1v[8] = {af1a.x, af1a.y, af1a.z, af1a.w, af1b.x, af1b.y, af1b.z, af1b.w};
        short8 ahi0, alo0, ahi1, alo1;
#pragma unroll
        for (int j = 0; j < 8; j++) {
            unsigned short h0 = f2bf_rne(a0v[j]);
            ahi0[j] = (short)h0;
            alo0[j] = (short)f2bf_rne(a0v[j] - bf2f(h0));
            unsigned short h1 = f2bf_rne(a1v[j]);
            ahi1[j] = (short)h1;
            alo1[j] = (short)f2bf_rne(a1v[j] - bf2f(h1));
        }
#pragma unroll
        for (int ct = 0; ct < 4; ct++) {
            acc[0][ct] = __builtin_amdgcn_mfma_f32_16x16x32_bf16(ahi0, bhi[ct], acc[0][ct], 0, 0, 0);
            acc[0][ct] = __builtin_amdgcn_mfma_f32_16x16x32_bf16(ahi0, blo[ct], acc[0][ct], 0, 0, 0);
            acc[0][ct] = __builtin_amdgcn_mfma_f32_16x16x32_bf16(alo0, bhi[ct], acc[0][ct], 0, 0, 0);
            acc[1][ct] = __builtin_amdgcn_mfma_f32_16x16x32_bf16(ahi1, bhi[ct], acc[1][ct], 0, 0, 0);
            acc[1][ct] = __builtin_amdgcn_mfma_f32_16x16x32_bf16(ahi1, blo[ct], acc[1][ct], 0, 0, 0);
            acc[1][ct] = __builtin_amdgcn_mfma_f32_16x16x32_bf16(alo1, bhi[ct], acc[1][ct], 0, 0, 0);
        }
    }
    // C/D layout: col = lane&15, row = (lane>>4)*4 + reg
#pragma unroll
    for (int rt = 0; rt < 2; rt++) {
#pragma unroll
        for (int i = 0; i < 4; i++) {
            int grow = rb0 + rt * 16 + kg * 4 + i;
            if (grow < NN) {
                unsigned short* dst = (unsigned short*)xw + (size_t)grow * HID + r;
#pragma unroll
                for (int ct = 0; ct < 4; ct++)
                    dst[ct * 16] = f2bf_rne(acc[rt][ct][i]);
            }
        }
    }
}

// ---- gather1: h[n,f] = relu(sum w'*xw[r,f] + dis^2*xw[n,f] + b1[f]) ----
__global__ __launch_bounds__(256) void gather1_kernel(const int* __restrict__ basev,
                                                      const int* __restrict__ endv,
                                                      const ull* __restrict__ eme,
                                                      const __hip_bfloat16* __restrict__ xw,
                                                      const float* __restrict__ dis,
                                                      const float* __restrict__ b,
                                                      float* __restrict__ h) {
    int n = blockIdx.x * 4 + (threadIdx.x >> 6);
    if (n >= NN) return;
    int lane = threadIdx.x & 63;
    int s = basev[n], t = endv[n];
    float acc = 0.f;
    int p = s;
    for (; p + 16 <= t; p += 16) {
        ull q[16];
#pragma unroll
        for (int j = 0; j < 16; j++) q[j] = __builtin_nontemporal_load(&eme[p + j]);
        float v[16];
#pragma unroll
        for (int j = 0; j < 16; j++) {
            unsigned src = (unsigned)q[j] & 0x1FFFFu;
            v[j] = __bfloat162float(xw[(src << 6) | lane]);
        }
#pragma unroll
        for (int j = 0; j < 16; j++)
            acc += __int_as_float((int)(q[j] >> 32)) * v[j];
    }
    for (; p + 8 <= t; p += 8) {
        ull q[8];
#pragma unroll
        for (int j = 0; j < 8; j++) q[j] = __builtin_nontemporal_load(&eme[p + j]);
        float v[8];
#pragma unroll
        for (int j = 0; j < 8; j++) {
            unsigned src = (unsigned)q[j] & 0x1FFFFu;
            v[j] = __bfloat162float(xw[(src << 6) | lane]);
        }
#pragma unroll
        for (int j = 0; j < 8; j++)
            acc += __int_as_float((int)(q[j] >> 32)) * v[j];
    }
    for (; p + 4 <= t; p += 4) {
        ull q[4];
#pragma unroll
        for (int j = 0; j < 4; j++) q[j] = __builtin_nontemporal_load(&eme[p + j]);
#pragma unroll
        for (int j = 0; j < 4; j++) {
            unsigned src = (unsigned)q[j] & 0x1FFFFu;
            acc += __int_as_float((int)(q[j] >> 32)) *
                   __bfloat162float(xw[(src << 6) | lane]);
        }
    }
    for (; p < t; ++p) {
        ull q = __builtin_nontemporal_load(&eme[p]);
        unsigned src = (unsigned)q & 0x1FFFFu;
        acc += __int_as_float((int)(q >> 32)) *
               __bfloat162float(xw[(src << 6) | lane]);
    }
    float d = dis[n];
    float v = acc + d * d * __bfloat162float(xw[((unsigned)n << 6) | lane]) + b[lane];
    h[(size_t)n * HID + lane] = fmaxf(v, 0.f);
}

// ---- GEMM2: hw2[N,64-padded](bf16) = h[N,64] @ W2[64,40]; rows padded to one 128B line ----
__global__ __launch_bounds__(256) void gemm2_kernel(const float* __restrict__ h,
                                                    const float* __restrict__ W,
                                                    __hip_bfloat16* __restrict__ hw) {
    __shared__ float hs[64][65];
    __shared__ float Ws[HID * NC];
    const int tid = threadIdx.x;
    const int base = blockIdx.x * 64;
    for (int v = tid; v < 1024; v += 256) {
        int r = v >> 4, q = v & 15;
        int gr = base + r;
        float4 hv = make_float4(0.f, 0.f, 0.f, 0.f);
        if (gr < NN) hv = *(const float4*)(h + (size_t)gr * HID + q * 4);
        hs[r][q * 4 + 0] = hv.x; hs[r][q * 4 + 1] = hv.y;
        hs[r][q * 4 + 2] = hv.z; hs[r][q * 4 + 3] = hv.w;
    }
    for (int v = tid; v < HID * NC; v += 256) Ws[v] = W[v];
    __syncthreads();
    const int tx = tid & 7;
    const int ty = tid >> 3;
    float acc[2][5] = {};
#pragma unroll 8
    for (int k = 0; k < HID; k++) {
        float h0 = hs[ty * 2 + 0][k];
        float h1 = hs[ty * 2 + 1][k];
        const float* wr = &Ws[k * NC + tx * 5];
        float w0 = wr[0], w1 = wr[1], w2 = wr[2], w3 = wr[3], w4 = wr[4];
        acc[0][0] += h0 * w0; acc[0][1] += h0 * w1; acc[0][2] += h0 * w2;
        acc[0][3] += h0 * w3; acc[0][4] += h0 * w4;
        acc[1][0] += h1 * w0; acc[1][1] += h1 * w1; acc[1][2] += h1 * w2;
        acc[1][3] += h1 * w3; acc[1][4] += h1 * w4;
    }
#pragma unroll
    for (int i = 0; i < 2; i++) {
        int gr = base + ty * 2 + i;
        if (gr < NN) {
#pragma unroll
            for (int c = 0; c < 5; c++)
                hw[(size_t)gr * 64 + tx * 5 + c] = __float2bfloat16(acc[i][c]);
        }
    }
}

// ---- gather2 + final: out = agg + dis^2*hw + b2 ; log_softmax fused ----
// hw rows are padded to stride 64 (one aligned 128B line); lanes >= NC read
// padding garbage whose accumulator is never used.
__global__ __launch_bounds__(256) void gather2_kernel(const int* __restrict__ basev,
                                                      const int* __restrict__ endv,
                                                      const ull* __restrict__ eme,
                                                      const __hip_bfloat16* __restrict__ hw,
                                                      const float* __restrict__ dis,
                                                      const float* __restrict__ b,
                                                      float* __restrict__ out) {
    int n = blockIdx.x * 4 + (threadIdx.x >> 6);
    if (n >= NN) return;
    int lane = threadIdx.x & 63;
    bool act = lane < NC;
    int s = basev[n], t = endv[n];
    float acc = 0.f;
    int p = s;
    for (; p + 16 <= t; p += 16) {
        ull q[16];
#pragma unroll
        for (int j = 0; j < 16; j++) q[j] = __builtin_nontemporal_load(&eme[p + j]);
        float v[16];
#pragma unroll
        for (int j = 0; j < 16; j++) {
            unsigned src = (unsigned)q[j] & 0x1FFFFu;
            v[j] = __bfloat162float(hw[(src << 6) | lane]);
        }
#pragma unroll
        for (int j = 0; j < 16; j++)
            acc += __int_as_float((int)(q[j] >> 32)) * v[j];
    }
    for (; p + 8 <= t; p += 8) {
        ull q[8];
#pragma unroll
        for (int j = 0; j < 8; j++) q[j] = __builtin_nontemporal_load(&eme[p + j]);
        float v[8];
#pragma unroll
        for (int j = 0; j < 8; j++) {
            unsigned src = (unsigned)q[j] & 0x1FFFFu;
            v[j] = __bfloat162float(hw[(src << 6) | lane]);
        }
#pragma unroll
        for (int j = 0; j < 8; j++)
            acc += __int_as_float((int)(q[j] >> 32)) * v[j];
    }
    for (; p + 4 <= t; p += 4) {
        ull q[4];
#pragma unroll
        for (int j = 0; j < 4; j++) q[j] = __builtin_nontemporal_load(&eme[p + j]);
#pragma unroll
        for (int j = 0; j < 4; j++) {
            unsigned src = (unsigned)q[j] & 0x1FFFFu;
            acc += __int_as_float((int)(q[j] >> 32)) *
                   __bfloat162float(hw[(src << 6) | lane]);
        }
    }
    for (; p < t; ++p) {
        ull q = __builtin_nontemporal_load(&eme[p]);
        unsigned src = (unsigned)q & 0x1FFFFu;
        acc += __int_as_float((int)(q >> 32)) *
               __bfloat162float(hw[(src << 6) | lane]);
    }
    float val = 0.f, v = -INFINITY;
    if (act) {
        float d = dis[n];
        val = acc + d * d * __bfloat162float(hw[((unsigned)n << 6) | lane]) + b[lane];
        v = val;
    }
    float m = v;
#pragma unroll
    for (int off = 32; off; off >>= 1) m = fmaxf(m, __shfl_xor(m, off));
    float e = act ? expf(val - m) : 0.f;
    float sum = e;
#pragma unroll
    for (int off = 32; off; off >>= 1) sum += __shfl_xor(sum, off);
    float lse = m + logf(sum);
    if (act) {
        size_t idx = (size_t)n * NC + lane;
        out[idx] = val;
        out[(size_t)NN * NC + idx] = val - lse;
    }
}

extern "C" void kernel_launch(void* const* d_in, const int* in_sizes, int n_in,
                              void* d_out, int out_size, void* d_ws, size_t ws_size,
                              hipStream_t stream) {
    const float* x    = (const float*)d_in[0];
    const int*   eidx = (const int*)d_in[1];
    const float* ew   = (const float*)d_in[2];
    const float* W1   = (const float*)d_in[3];
    const float* b1   = (const float*)d_in[4];
    const float* W2   = (const float*)d_in[5];
    const float* b2   = (const float*)d_in[6];
    float* out = (float*)d_out;

    const int* row = eidx;
    const int* col = eidx + EE;

    char* ws = (char*)d_ws;
    int*   bucket_cnt  = (int*)ws;               ws += 256 * 4;
    int*   bucket_base = (int*)ws;               ws += 256 * 4;
    float* dis    = (float*)ws;                  ws += NN * 4;
    int*   basev  = (int*)ws;                    ws += NN * 4;
    int*   endv   = (int*)ws;                    ws += NN * 4;
    int2*  eme    = (int2*)ws;                   ws += (size_t)EE * 8;
    __hip_bfloat16* xw = (__hip_bfloat16*)ws;    ws += (size_t)NN * HID * 2;
    // staging (16.06 MB) and h (25.6 MB) are never live simultaneously: union them
    char* unionp = ws;                           ws += (size_t)NN * HID * 4;
    int2*  staging = (int2*)unionp;              // NB*BCAP*8 = 16.06 MB <= 25.6 MB
    float* h       = (float*)unionp;
    __hip_bfloat16* hw2 = (__hip_bfloat16*)ws;   ws += (size_t)NN * 64 * 2;  // stride-64 padded
    unsigned short* w1hi = (unsigned short*)ws;  ws += (size_t)HID * FIN * 2; // B^T bf16 hi
    unsigned short* w1lo = (unsigned short*)ws;  ws += (size_t)HID * FIN * 2; // B^T bf16 lo

    hipMemsetAsync(bucket_cnt, 0, 256 * 4, stream);

    bucket_kernel<<<NBKB, 256, 0, stream>>>(row, col, ew, bucket_cnt, staging);
    bscan_w1cvt_kernel<<<5, 256, 0, stream>>>(bucket_cnt, bucket_base, W1, w1hi, w1lo);
    build_count_kernel<<<NB, 512, 0, stream>>>(staging, bucket_cnt, bucket_base,
                                               basev, endv, dis);
    build_place_kernel<<<NB, 512, 0, stream>>>(staging, bucket_cnt, basev, dis, eme);
    gemm1_mfma_kernel<<<(NN + 127) / 128, 256, 0, stream>>>(x, w1hi, w1lo, xw);
    gather1_kernel<<<(NN + 3) / 4, 256, 0, stream>>>(basev, endv, (const ull*)eme,
                                                     xw, dis, b1, h);
    gemm2_kernel<<<(NN + 63) / 64, 256, 0, stream>>>(h, W2, hw2);
    gather2_kernel<<<(NN + 3) / 4, 256, 0, stream>>>(basev, endv, (const ull*)eme,
                                                     hw2, dis, b2, out);
}

// Round 5
// 428.871 us; speedup vs baseline: 1.1919x; 1.0032x over previous
//
#include <hip/hip_runtime.h>
#include <hip/hip_bf16.h>
#include <math.h>

#define NN 100000
#define EE 1600000
#define FIN 256
#define HID 64
#define NC 40
#define NB 196        // destination buckets of 512 nodes (196*512 = 100352)
#define BCAP 10240    // staging capacity per bucket (mean 8192, +22 sigma)
#define CHUNK 2048    // edges per bucket_kernel block
#define NBKB ((EE + CHUNK - 1) / CHUNK)   // 782

typedef unsigned long long ull;
typedef __attribute__((ext_vector_type(8))) short short8;
typedef __attribute__((ext_vector_type(4))) float f32x4;

__device__ __forceinline__ unsigned short f2bf_rne(float f) {
    unsigned u = __float_as_uint(f);
    u += 0x7FFFu + ((u >> 16) & 1u);
    return (unsigned short)(u >> 16);
}
__device__ __forceinline__ float bf2f(unsigned short b) {
    return __uint_as_float((unsigned)b << 16);
}

// ---- stage edges into destination buckets; LDS-reorder by bucket for coalesced writes ----
__global__ __launch_bounds__(256) void bucket_kernel(const int* __restrict__ row,
                                                     const int* __restrict__ col,
                                                     const float* __restrict__ w,
                                                     int* __restrict__ bucket_cnt,
                                                     int2* __restrict__ staging) {
    __shared__ int2 spay[CHUNK];            // 16 KB  original-order payload
    __shared__ int2 sorted[CHUNK];          // 16 KB  bucket-ordered payload
    __shared__ unsigned char sb[CHUNK];     // 2 KB   bucket id per original slot
    __shared__ unsigned char sbk[CHUNK];    // 2 KB   bucket id per sorted slot
    __shared__ int lcnt[NB], lofs[NB], lstart[NB];
    __shared__ int sscan[256];
    const int tid = threadIdx.x;
    const int e0 = blockIdx.x * CHUNK;
    const int nE = min(CHUNK, EE - e0);
    for (int i = tid; i < nE; i += 256) {
        int e = e0 + i;
        int c = col[e];
        sb[i] = (unsigned char)(c >> 9);
        spay[i] = make_int2(((c & 511) << 17) | row[e], __float_as_int(w[e]));
    }
    for (int i = tid; i < NB; i += 256) lcnt[i] = 0;
    __syncthreads();
    for (int i = tid; i < nE; i += 256) atomicAdd(&lcnt[sb[i]], 1);
    __syncthreads();
    // exclusive scan of lcnt over NB (<=256)
    int v = (tid < NB) ? lcnt[tid] : 0;
    sscan[tid] = v;
    __syncthreads();
    for (int off = 1; off < 256; off <<= 1) {
        int u = (tid >= off) ? sscan[tid - off] : 0;
        __syncthreads();
        sscan[tid] += u;
        __syncthreads();
    }
    if (tid < NB) {
        lofs[tid] = sscan[tid] - v;                       // local exclusive prefix
        lstart[tid] = v ? atomicAdd(&bucket_cnt[tid], v) : 0;  // global base for this block's run
        lcnt[tid] = 0;
    }
    __syncthreads();
    // reorder into bucket-contiguous LDS
    for (int i = tid; i < nE; i += 256) {
        int b = sb[i];
        int p = lofs[b] + atomicAdd(&lcnt[b], 1);
        sorted[p] = spay[i];
        sbk[p] = (unsigned char)b;
    }
    __syncthreads();
    // write out: consecutive threads -> consecutive slots of the same bucket
    for (int p = tid; p < nE; p += 256) {
        int b = sbk[p];
        int slot = lstart[b] + (p - lofs[b]);
        if (slot < BCAP) staging[(size_t)b * BCAP + slot] = sorted[p];
    }
}

// ---- block 0: exclusive scan of bucket counts; blocks 1..4: W1 -> B^T bf16 hi/lo tables ----
__global__ __launch_bounds__(256) void bscan_w1cvt_kernel(int* __restrict__ bucket_cnt,
                                                          int* __restrict__ bucket_base,
                                                          const float* __restrict__ W1,
                                                          unsigned short* __restrict__ w1hi,
                                                          unsigned short* __restrict__ w1lo) {
    if (blockIdx.x == 0) {
        __shared__ int sd[256];
        int t = threadIdx.x;
        int v = (t < NB) ? min(bucket_cnt[t], BCAP) : 0;
        sd[t] = v;
        __syncthreads();
        for (int off = 1; off < 256; off <<= 1) {
            int u = (t >= off) ? sd[t - off] : 0;
            __syncthreads();
            sd[t] += u;
            __syncthreads();
        }
        if (t < NB) { bucket_base[t] = sd[t] - v; bucket_cnt[t] = v; }
    } else {
        int b = blockIdx.x - 1;          // 0..3
        for (int i = threadIdx.x; i < 4096; i += 256) {
            int e = b * 4096 + i;        // e = c*256 + k  (B^T layout)
            int c = e >> 8, k = e & 255;
            float v = W1[(size_t)k * HID + c];
            unsigned short h = f2bf_rne(v);
            w1hi[e] = h;
            w1lo[e] = f2bf_rne(v - bf2f(h));
        }
    }
}

// ---- build pass A: per-dest count + weighted degree (LDS atomics), scan, basev/endv, dis ----
__global__ __launch_bounds__(512) void build_count_kernel(const int2* __restrict__ staging,
                                                          const int* __restrict__ bucket_cnt,
                                                          const int* __restrict__ bucket_base,
                                                          int* __restrict__ basev,
                                                          int* __restrict__ endv,
                                                          float* __restrict__ dis) {
    __shared__ int dcnt[512];
    __shared__ float dsum[512];
    __shared__ int sscan[512];
    const int t = threadIdx.x;
    const int b = blockIdx.x;
    const int nE = bucket_cnt[b];
    const int ebase = bucket_base[b];
    const int2* st = staging + (size_t)b * BCAP;
    dcnt[t] = 0; dsum[t] = 0.f;
    __syncthreads();
    for (int i = t; i < nE; i += 512) {
        int2 p = st[i];
        int d = p.x >> 17;
        atomicAdd(&dcnt[d], 1);
        atomicAdd(&dsum[d], __int_as_float(p.y));
    }
    __syncthreads();
    int c = dcnt[t];
    sscan[t] = c;
    __syncthreads();
    for (int off = 1; off < 512; off <<= 1) {
        int u = (t >= off) ? sscan[t - off] : 0;
        __syncthreads();
        sscan[t] += u;
        __syncthreads();
    }
    int gb = ebase + sscan[t] - c;   // exclusive prefix
    int gd = b * 512 + t;
    if (gd < NN) {
        basev[gd] = gb;
        endv[gd] = gb + c;
        dis[gd] = rsqrtf(dsum[t] + 1.0f);   // self-loop weight 1
    }
}

// ---- build pass B: place edges with fully-normalized weight (dis complete, L2-resident) ----
__global__ __launch_bounds__(512) void build_place_kernel(const int2* __restrict__ staging,
                                                          const int* __restrict__ bucket_cnt,
                                                          const int* __restrict__ basev,
                                                          const float* __restrict__ dis,
                                                          int2* __restrict__ eme) {
    __shared__ int dcur[512];
    __shared__ float sdis[512];
    const int t = threadIdx.x;
    const int b = blockIdx.x;
    const int nE = bucket_cnt[b];
    const int2* st = staging + (size_t)b * BCAP;
    const int gd = b * 512 + t;
    dcur[t] = (gd < NN) ? basev[gd] : 0;
    sdis[t] = (gd < NN) ? dis[gd] : 0.f;
    __syncthreads();
    for (int i = t; i < nE; i += 512) {
        int2 p = st[i];
        int d = p.x >> 17;
        int src = p.x & 0x1FFFF;
        int pos = atomicAdd(&dcur[d], 1);
        float wn = __int_as_float(p.y) * dis[src] * sdis[d];
        eme[pos] = make_int2(src, __float_as_int(wn));
    }
}

// ---- GEMM1 (MFMA, split-bf16 f32 emulation): xw[N,64](bf16) = x[N,256] @ W1[256,64] ----
__global__ __launch_bounds__(256) void gemm1_mfma_kernel(const float* __restrict__ x,
                                                         const unsigned short* __restrict__ w1hi,
                                                         const unsigned short* __restrict__ w1lo,
                                                         __hip_bfloat16* __restrict__ xw) {
    const int tid = threadIdx.x;
    const int wid = tid >> 6;
    const int l   = tid & 63;
    const int r   = l & 15;        // A row within 16-tile / B col within 16-tile
    const int kg  = l >> 4;        // k-group 0..3 (8 contiguous k each)
    const int rb0 = blockIdx.x * 128 + wid * 32;   // wave's first row

    f32x4 acc[2][4];
#pragma unroll
    for (int i = 0; i < 2; i++)
#pragma unroll
        for (int j = 0; j < 4; j++) acc[i][j] = (f32x4){0.f, 0.f, 0.f, 0.f};

    int row0 = rb0 + r;
    int row1 = rb0 + 16 + r;
    int row0c = row0 < NN ? row0 : NN - 1;   // clamp loads; stores are guarded
    int row1c = row1 < NN ? row1 : NN - 1;
    const float* a0p = x + (size_t)row0c * FIN + kg * 8;
    const float* a1p = x + (size_t)row1c * FIN + kg * 8;

#pragma unroll
    for (int ks = 0; ks < 8; ks++) {
        // B fragments for 4 col-tiles: col = ct*16 + r, k in [ks*32 + kg*8, +8)
        short8 bhi[4], blo[4];
#pragma unroll
        for (int ct = 0; ct < 4; ct++) {
            size_t off = (size_t)(ct * 16 + r) * FIN + ks * 32 + kg * 8;
            bhi[ct] = *(const short8*)(w1hi + off);
            blo[ct] = *(const short8*)(w1lo + off);
        }
        // A: 8 contiguous f32 per row-tile
        float4 af0a = *(const float4*)(a0p + ks * 32);
        float4 af0b = *(const float4*)(a0p + ks * 32 + 4);
        float4 af1a = *(const float4*)(a1p + ks * 32);
        float4 af1b = *(const float4*)(a1p + ks * 32 + 4);
        float a0v[8] = {af0a.x, af0a.y, af0a.z, af0a.w, af0b.x, af0b.y, af0b.z, af0b.w};
        float a1v[8] = {af1a.x, af1a.y, af1a.z, af1a.w, af1b.x, af1b.y, af1b.z, af1b.w};
        short8 ahi0, alo0, ahi1, alo1;
#pragma unroll
        for (int j = 0; j < 8; j++) {
            unsigned short h0 = f2bf_rne(a0v[j]);
            ahi0[j] = (short)h0;
            alo0[j] = (short)f2bf_rne(a0v[j] - bf2f(h0));
            unsigned short h1 = f2bf_rne(a1v[j]);
            ahi1[j] = (short)h1;
            alo1[j] = (short)f2bf_rne(a1v[j] - bf2f(h1));
        }
#pragma unroll
        for (int ct = 0; ct < 4; ct++) {
            acc[0][ct] = __builtin_amdgcn_mfma_f32_16x16x32_bf16(ahi0, bhi[ct], acc[0][ct], 0, 0, 0);
            acc[0][ct] = __builtin_amdgcn_mfma_f32_16x16x32_bf16(ahi0, blo[ct], acc[0][ct], 0, 0, 0);
            acc[0][ct] = __builtin_amdgcn_mfma_f32_16x16x32_bf16(alo0, bhi[ct], acc[0][ct], 0, 0, 0);
            acc[1][ct] = __builtin_amdgcn_mfma_f32_16x16x32_bf16(ahi1, bhi[ct], acc[1][ct], 0, 0, 0);
            acc[1][ct] = __builtin_amdgcn_mfma_f32_16x16x32_bf16(ahi1, blo[ct], acc[1][ct], 0, 0, 0);
            acc[1][ct] = __builtin_amdgcn_mfma_f32_16x16x32_bf16(alo1, bhi[ct], acc[1][ct], 0, 0, 0);
        }
    }
    // C/D layout: col = lane&15, row = (lane>>4)*4 + reg
#pragma unroll
    for (int rt = 0; rt < 2; rt++) {
#pragma unroll
        for (int i = 0; i < 4; i++) {
            int grow = rb0 + rt * 16 + kg * 4 + i;
            if (grow < NN) {
                unsigned short* dst = (unsigned short*)xw + (size_t)grow * HID + r;
#pragma unroll
                for (int ct = 0; ct < 4; ct++)
                    dst[ct * 16] = f2bf_rne(acc[rt][ct][i]);
            }
        }
    }
}

// ---- gather1: 2 edges/wave-slot, 2 features/lane ----
// Lanes 0-31 process even edges, 32-63 odd edges; lane loads one dword (2 bf16)
// of the 64-elem row. Halves combined via shfl_xor(32) at the end.
__global__ __launch_bounds__(256) void gather1_kernel(const int* __restrict__ basev,
                                                      const int* __restrict__ endv,
                                                      const ull* __restrict__ eme,
                                                      const unsigned* __restrict__ xw32,
                                                      const float* __restrict__ dis,
                                                      const float* __restrict__ b,
                                                      float* __restrict__ h) {
    int n = blockIdx.x * 4 + (threadIdx.x >> 6);
    if (n >= NN) return;
    int lane = threadIdx.x & 63;
    int half = lane >> 5;          // 0: even edges, 1: odd edges
    int fl = lane & 31;            // feature-pair index (features 2fl, 2fl+1)
    int s = basev[n], t = endv[n];
    int deg = t - s;
    float acc0 = 0.f, acc1 = 0.f;
    int nb = deg >> 4;             // full 16-edge batches (8 per half)
    int p = s + half;
    for (int bi = 0; bi < nb; bi++, p += 16) {
        ull q[8];
#pragma unroll
        for (int j = 0; j < 8; j++) q[j] = __builtin_nontemporal_load(&eme[p + 2 * j]);
        unsigned u[8];
#pragma unroll
        for (int j = 0; j < 8; j++) {
            unsigned src = (unsigned)q[j] & 0x1FFFFu;
            u[j] = xw32[(src << 5) | fl];
        }
#pragma unroll
        for (int j = 0; j < 8; j++) {
            float w = __int_as_float((int)(q[j] >> 32));
            acc0 += w * __uint_as_float(u[j] << 16);
            acc1 += w * __uint_as_float(u[j] & 0xFFFF0000u);
        }
    }
    int p2 = s + (nb << 4);
    if (t - p2 >= 8) {             // mid batch: 8 edges (4 per half)
        p = p2 + half;
        ull q[4];
#pragma unroll
        for (int j = 0; j < 4; j++) q[j] = __builtin_nontemporal_load(&eme[p + 2 * j]);
        unsigned u[4];
#pragma unroll
        for (int j = 0; j < 4; j++) {
            unsigned src = (unsigned)q[j] & 0x1FFFFu;
            u[j] = xw32[(src << 5) | fl];
        }
#pragma unroll
        for (int j = 0; j < 4; j++) {
            float w = __int_as_float((int)(q[j] >> 32));
            acc0 += w * __uint_as_float(u[j] << 16);
            acc1 += w * __uint_as_float(u[j] & 0xFFFF0000u);
        }
        p2 += 8;
    }
    for (p = p2 + half; p < t; p += 2) {
        ull q = __builtin_nontemporal_load(&eme[p]);
        unsigned src = (unsigned)q & 0x1FFFFu;
        unsigned u = xw32[(src << 5) | fl];
        float w = __int_as_float((int)(q >> 32));
        acc0 += w * __uint_as_float(u << 16);
        acc1 += w * __uint_as_float(u & 0xFFFF0000u);
    }
    acc0 += __shfl_xor(acc0, 32);
    acc1 += __shfl_xor(acc1, 32);
    float d = dis[n];
    unsigned un = xw32[((unsigned)n << 5) | fl];
    float2 bv = *(const float2*)(b + 2 * fl);
    float v0 = acc0 + d * d * __uint_as_float(un << 16) + bv.x;
    float v1 = acc1 + d * d * __uint_as_float(un & 0xFFFF0000u) + bv.y;
    if (lane < 32) {
        *(float2*)(h + (size_t)n * HID + 2 * fl) = make_float2(fmaxf(v0, 0.f), fmaxf(v1, 0.f));
    }
}

// ---- GEMM2: hw2[N,64-padded](bf16) = h[N,64] @ W2[64,40]; rows padded to one 128B line ----
__global__ __launch_bounds__(256) void gemm2_kernel(const float* __restrict__ h,
                                                    const float* __restrict__ W,
                                                    __hip_bfloat16* __restrict__ hw) {
    __shared__ float hs[64][65];
    __shared__ float Ws[HID * NC];
    const int tid = threadIdx.x;
    const int base = blockIdx.x * 64;
    for (int v = tid; v < 1024; v += 256) {
        int r = v >> 4, q = v & 15;
        int gr = base + r;
        float4 hv = make_float4(0.f, 0.f, 0.f, 0.f);
        if (gr < NN) hv = *(const float4*)(h + (size_t)gr * HID + q * 4);
        hs[r][q * 4 + 0] = hv.x; hs[r][q * 4 + 1] = hv.y;
        hs[r][q * 4 + 2] = hv.z; hs[r][q * 4 + 3] = hv.w;
    }
    for (int v = tid; v < HID * NC; v += 256) Ws[v] = W[v];
    __syncthreads();
    const int tx = tid & 7;
    const int ty = tid >> 3;
    float acc[2][5] = {};
#pragma unroll 8
    for (int k = 0; k < HID; k++) {
        float h0 = hs[ty * 2 + 0][k];
        float h1 = hs[ty * 2 + 1][k];
        const float* wr = &Ws[k * NC + tx * 5];
        float w0 = wr[0], w1 = wr[1], w2 = wr[2], w3 = wr[3], w4 = wr[4];
        acc[0][0] += h0 * w0; acc[0][1] += h0 * w1; acc[0][2] += h0 * w2;
        acc[0][3] += h0 * w3; acc[0][4] += h0 * w4;
        acc[1][0] += h1 * w0; acc[1][1] += h1 * w1; acc[1][2] += h1 * w2;
        acc[1][3] += h1 * w3; acc[1][4] += h1 * w4;
    }
#pragma unroll
    for (int i = 0; i < 2; i++) {
        int gr = base + ty * 2 + i;
        if (gr < NN) {
#pragma unroll
            for (int c = 0; c < 5; c++)
                hw[(size_t)gr * 64 + tx * 5 + c] = __float2bfloat16(acc[i][c]);
        }
    }
}

// ---- gather2 + final: 2 edges/wave-slot, 2 classes/lane; log_softmax fused ----
// hw rows padded to stride 64 (one aligned 128B line); feature-pairs fl<20 are real.
__global__ __launch_bounds__(256) void gather2_kernel(const int* __restrict__ basev,
                                                      const int* __restrict__ endv,
                                                      const ull* __restrict__ eme,
                                                      const unsigned* __restrict__ hw32,
                                                      const float* __restrict__ dis,
                                                      const float* __restrict__ b,
                                                      float* __restrict__ out) {
    int n = blockIdx.x * 4 + (threadIdx.x >> 6);
    if (n >= NN) return;
    int lane = threadIdx.x & 63;
    int half = lane >> 5;
    int fl = lane & 31;
    bool act = fl < 20;            // classes 2fl, 2fl+1 < 40
    int s = basev[n], t = endv[n];
    int deg = t - s;
    float acc0 = 0.f, acc1 = 0.f;
    int nb = deg >> 4;
    int p = s + half;
    for (int bi = 0; bi < nb; bi++, p += 16) {
        ull q[8];
#pragma unroll
        for (int j = 0; j < 8; j++) q[j] = __builtin_nontemporal_load(&eme[p + 2 * j]);
        unsigned u[8];
#pragma unroll
        for (int j = 0; j < 8; j++) {
            unsigned src = (unsigned)q[j] & 0x1FFFFu;
            u[j] = hw32[(src << 5) | fl];
        }
#pragma unroll
        for (int j = 0; j < 8; j++) {
            float w = __int_as_float((int)(q[j] >> 32));
            acc0 += w * __uint_as_float(u[j] << 16);
            acc1 += w * __uint_as_float(u[j] & 0xFFFF0000u);
        }
    }
    int p2 = s + (nb << 4);
    if (t - p2 >= 8) {
        p = p2 + half;
        ull q[4];
#pragma unroll
        for (int j = 0; j < 4; j++) q[j] = __builtin_nontemporal_load(&eme[p + 2 * j]);
        unsigned u[4];
#pragma unroll
        for (int j = 0; j < 4; j++) {
            unsigned src = (unsigned)q[j] & 0x1FFFFu;
            u[j] = hw32[(src << 5) | fl];
        }
#pragma unroll
        for (int j = 0; j < 4; j++) {
            float w = __int_as_float((int)(q[j] >> 32));
            acc0 += w * __uint_as_float(u[j] << 16);
            acc1 += w * __uint_as_float(u[j] & 0xFFFF0000u);
        }
        p2 += 8;
    }
    for (p = p2 + half; p < t; p += 2) {
        ull q = __builtin_nontemporal_load(&eme[p]);
        unsigned src = (unsigned)q & 0x1FFFFu;
        unsigned u = hw32[(src << 5) | fl];
        float w = __int_as_float((int)(q >> 32));
        acc0 += w * __uint_as_float(u << 16);
        acc1 += w * __uint_as_float(u & 0xFFFF0000u);
    }
    acc0 += __shfl_xor(acc0, 32);
    acc1 += __shfl_xor(acc1, 32);
    float v0 = 0.f, v1 = 0.f, m = -INFINITY;
    if (act) {
        float d = dis[n];
        unsigned un = hw32[((unsigned)n << 5) | fl];
        float2 bv = *(const float2*)(b + 2 * fl);
        v0 = acc0 + d * d * __uint_as_float(un << 16) + bv.x;
        v1 = acc1 + d * d * __uint_as_float(un & 0xFFFF0000u) + bv.y;
        m = fmaxf(v0, v1);
    }
#pragma unroll
    for (int off = 16; off; off >>= 1) m = fmaxf(m, __shfl_xor(m, off));
    float e0 = act ? expf(v0 - m) : 0.f;
    float e1 = act ? expf(v1 - m) : 0.f;
    float sum = e0 + e1;
#pragma unroll
    for (int off = 16; off; off >>= 1) sum += __shfl_xor(sum, off);
    float lse = m + logf(sum);
    if (act && lane < 32) {
        size_t idx = (size_t)n * NC + 2 * fl;
        *(float2*)(out + idx) = make_float2(v0, v1);
        *(float2*)(out + (size_t)NN * NC + idx) = make_float2(v0 - lse, v1 - lse);
    }
}

extern "C" void kernel_launch(void* const* d_in, const int* in_sizes, int n_in,
                              void* d_out, int out_size, void* d_ws, size_t ws_size,
                              hipStream_t stream) {
    const float* x    = (const float*)d_in[0];
    const int*   eidx = (const int*)d_in[1];
    const float* ew   = (const float*)d_in[2];
    const float* W1   = (const float*)d_in[3];
    const float* b1   = (const float*)d_in[4];
    const float* W2   = (const float*)d_in[5];
    const float* b2   = (const float*)d_in[6];
    float* out = (float*)d_out;

    const int* row = eidx;
    const int* col = eidx + EE;

    char* ws = (char*)d_ws;
    int*   bucket_cnt  = (int*)ws;               ws += 256 * 4;
    int*   bucket_base = (int*)ws;               ws += 256 * 4;
    float* dis    = (float*)ws;                  ws += NN * 4;
    int*   basev  = (int*)ws;                    ws += NN * 4;
    int*   endv   = (int*)ws;                    ws += NN * 4;
    int2*  eme    = (int2*)ws;                   ws += (size_t)EE * 8;
    __hip_bfloat16* xw = (__hip_bfloat16*)ws;    ws += (size_t)NN * HID * 2;
    // staging (16.06 MB) and h (25.6 MB) are never live simultaneously: union them
    char* unionp = ws;                           ws += (size_t)NN * HID * 4;
    int2*  staging = (int2*)unionp;              // NB*BCAP*8 = 16.06 MB <= 25.6 MB
    float* h       = (float*)unionp;
    __hip_bfloat16* hw2 = (__hip_bfloat16*)ws;   ws += (size_t)NN * 64 * 2;  // stride-64 padded
    unsigned short* w1hi = (unsigned short*)ws;  ws += (size_t)HID * FIN * 2; // B^T bf16 hi
    unsigned short* w1lo = (unsigned short*)ws;  ws += (size_t)HID * FIN * 2; // B^T bf16 lo

    hipMemsetAsync(bucket_cnt, 0, 256 * 4, stream);

    bucket_kernel<<<NBKB, 256, 0, stream>>>(row, col, ew, bucket_cnt, staging);
    bscan_w1cvt_kernel<<<5, 256, 0, stream>>>(bucket_cnt, bucket_base, W1, w1hi, w1lo);
    build_count_kernel<<<NB, 512, 0, stream>>>(staging, bucket_cnt, bucket_base,
                                               basev, endv, dis);
    build_place_kernel<<<NB, 512, 0, stream>>>(staging, bucket_cnt, basev, dis, eme);
    gemm1_mfma_kernel<<<(NN + 127) / 128, 256, 0, stream>>>(x, w1hi, w1lo, xw);
    gather1_kernel<<<(NN + 3) / 4, 256, 0, stream>>>(basev, endv, (const ull*)eme,
                                                     (const unsigned*)xw, dis, b1, h);
    gemm2_kernel<<<(NN + 63) / 64, 256, 0, stream>>>(h, W2, hw2);
    gather2_kernel<<<(NN + 3) / 4, 256, 0, stream>>>(basev, endv, (const ull*)eme,
                                                     (const unsigned*)hw2, dis, b2, out);
}

// Round 6
// 411.947 us; speedup vs baseline: 1.2408x; 1.0411x over previous
//
#include <hip/hip_runtime.h>
#include <hip/hip_bf16.h>
#include <math.h>

#define NN 100000
#define EE 1600000
#define FIN 256
#define HID 64
#define NC 40
#define NB 196        // destination buckets of 512 nodes (196*512 = 100352)
#define BCAP 10240    // staging capacity per bucket (mean 8192, +22 sigma)
#define CHUNK 2048    // edges per bucket_kernel block
#define NBKB ((EE + CHUNK - 1) / CHUNK)   // 782

typedef unsigned long long ull;
typedef __attribute__((ext_vector_type(8))) short short8;
typedef __attribute__((ext_vector_type(4))) float f32x4;

__device__ __forceinline__ unsigned short f2bf_rne(float f) {
    unsigned u = __float_as_uint(f);
    u += 0x7FFFu + ((u >> 16) & 1u);
    return (unsigned short)(u >> 16);
}
__device__ __forceinline__ float bf2f(unsigned short b) {
    return __uint_as_float((unsigned)b << 16);
}

// ---- stage edges into destination buckets; LDS-reorder by bucket for coalesced writes ----
__global__ __launch_bounds__(256) void bucket_kernel(const int* __restrict__ row,
                                                     const int* __restrict__ col,
                                                     const float* __restrict__ w,
                                                     int* __restrict__ bucket_cnt,
                                                     int2* __restrict__ staging) {
    __shared__ int2 spay[CHUNK];            // 16 KB  original-order payload
    __shared__ int2 sorted[CHUNK];          // 16 KB  bucket-ordered payload
    __shared__ unsigned char sb[CHUNK];     // 2 KB   bucket id per original slot
    __shared__ unsigned char sbk[CHUNK];    // 2 KB   bucket id per sorted slot
    __shared__ int lcnt[NB], lofs[NB], lstart[NB];
    __shared__ int sscan[256];
    const int tid = threadIdx.x;
    const int e0 = blockIdx.x * CHUNK;
    const int nE = min(CHUNK, EE - e0);
    for (int i = tid; i < nE; i += 256) {
        int e = e0 + i;
        int c = col[e];
        sb[i] = (unsigned char)(c >> 9);
        spay[i] = make_int2(((c & 511) << 17) | row[e], __float_as_int(w[e]));
    }
    for (int i = tid; i < NB; i += 256) lcnt[i] = 0;
    __syncthreads();
    for (int i = tid; i < nE; i += 256) atomicAdd(&lcnt[sb[i]], 1);
    __syncthreads();
    // exclusive scan of lcnt over NB (<=256)
    int v = (tid < NB) ? lcnt[tid] : 0;
    sscan[tid] = v;
    __syncthreads();
    for (int off = 1; off < 256; off <<= 1) {
        int u = (tid >= off) ? sscan[tid - off] : 0;
        __syncthreads();
        sscan[tid] += u;
        __syncthreads();
    }
    if (tid < NB) {
        lofs[tid] = sscan[tid] - v;                       // local exclusive prefix
        lstart[tid] = v ? atomicAdd(&bucket_cnt[tid], v) : 0;  // global base for this block's run
        lcnt[tid] = 0;
    }
    __syncthreads();
    // reorder into bucket-contiguous LDS
    for (int i = tid; i < nE; i += 256) {
        int b = sb[i];
        int p = lofs[b] + atomicAdd(&lcnt[b], 1);
        sorted[p] = spay[i];
        sbk[p] = (unsigned char)b;
    }
    __syncthreads();
    // write out: consecutive threads -> consecutive slots of the same bucket
    for (int p = tid; p < nE; p += 256) {
        int b = sbk[p];
        int slot = lstart[b] + (p - lofs[b]);
        if (slot < BCAP) staging[(size_t)b * BCAP + slot] = sorted[p];
    }
}

// ---- block 0: exclusive scan of bucket counts; blocks 1..4: W1 -> B^T bf16 hi/lo tables ----
__global__ __launch_bounds__(256) void bscan_w1cvt_kernel(int* __restrict__ bucket_cnt,
                                                          int* __restrict__ bucket_base,
                                                          const float* __restrict__ W1,
                                                          unsigned short* __restrict__ w1hi,
                                                          unsigned short* __restrict__ w1lo) {
    if (blockIdx.x == 0) {
        __shared__ int sd[256];
        int t = threadIdx.x;
        int v = (t < NB) ? min(bucket_cnt[t], BCAP) : 0;
        sd[t] = v;
        __syncthreads();
        for (int off = 1; off < 256; off <<= 1) {
            int u = (t >= off) ? sd[t - off] : 0;
            __syncthreads();
            sd[t] += u;
            __syncthreads();
        }
        if (t < NB) { bucket_base[t] = sd[t] - v; bucket_cnt[t] = v; }
    } else {
        int b = blockIdx.x - 1;          // 0..3
        for (int i = threadIdx.x; i < 4096; i += 256) {
            int e = b * 4096 + i;        // e = c*256 + k  (B^T layout)
            int c = e >> 8, k = e & 255;
            float v = W1[(size_t)k * HID + c];
            unsigned short h = f2bf_rne(v);
            w1hi[e] = h;
            w1lo[e] = f2bf_rne(v - bf2f(h));
        }
    }
}

// ---- build pass A: per-dest count + weighted degree (LDS atomics), scan, basev/endv, dis ----
__global__ __launch_bounds__(512) void build_count_kernel(const int2* __restrict__ staging,
                                                          const int* __restrict__ bucket_cnt,
                                                          const int* __restrict__ bucket_base,
                                                          int* __restrict__ basev,
                                                          int* __restrict__ endv,
                                                          float* __restrict__ dis) {
    __shared__ int dcnt[512];
    __shared__ float dsum[512];
    __shared__ int sscan[512];
    const int t = threadIdx.x;
    const int b = blockIdx.x;
    const int nE = bucket_cnt[b];
    const int ebase = bucket_base[b];
    const int2* st = staging + (size_t)b * BCAP;
    dcnt[t] = 0; dsum[t] = 0.f;
    __syncthreads();
    for (int i = t; i < nE; i += 512) {
        int2 p = st[i];
        int d = p.x >> 17;
        atomicAdd(&dcnt[d], 1);
        atomicAdd(&dsum[d], __int_as_float(p.y));
    }
    __syncthreads();
    int c = dcnt[t];
    sscan[t] = c;
    __syncthreads();
    for (int off = 1; off < 512; off <<= 1) {
        int u = (t >= off) ? sscan[t - off] : 0;
        __syncthreads();
        sscan[t] += u;
        __syncthreads();
    }
    int gb = ebase + sscan[t] - c;   // exclusive prefix
    int gd = b * 512 + t;
    if (gd < NN) {
        basev[gd] = gb;
        endv[gd] = gb + c;
        dis[gd] = rsqrtf(dsum[t] + 1.0f);   // self-loop weight 1
    }
}

// ---- build pass B: place edges with fully-normalized weight (dis complete, L2-resident) ----
__global__ __launch_bounds__(512) void build_place_kernel(const int2* __restrict__ staging,
                                                          const int* __restrict__ bucket_cnt,
                                                          const int* __restrict__ basev,
                                                          const float* __restrict__ dis,
                                                          int2* __restrict__ eme) {
    __shared__ int dcur[512];
    __shared__ float sdis[512];
    const int t = threadIdx.x;
    const int b = blockIdx.x;
    const int nE = bucket_cnt[b];
    const int2* st = staging + (size_t)b * BCAP;
    const int gd = b * 512 + t;
    dcur[t] = (gd < NN) ? basev[gd] : 0;
    sdis[t] = (gd < NN) ? dis[gd] : 0.f;
    __syncthreads();
    for (int i = t; i < nE; i += 512) {
        int2 p = st[i];
        int d = p.x >> 17;
        int src = p.x & 0x1FFFF;
        int pos = atomicAdd(&dcur[d], 1);
        float wn = __int_as_float(p.y) * dis[src] * sdis[d];
        eme[pos] = make_int2(src, __float_as_int(wn));
    }
}

// ---- GEMM1 (MFMA, split-bf16 f32 emulation): xw[N,64](bf16) = x[N,256] @ W1[256,64] ----
__global__ __launch_bounds__(256) void gemm1_mfma_kernel(const float* __restrict__ x,
                                                         const unsigned short* __restrict__ w1hi,
                                                         const unsigned short* __restrict__ w1lo,
                                                         __hip_bfloat16* __restrict__ xw) {
    const int tid = threadIdx.x;
    const int wid = tid >> 6;
    const int l   = tid & 63;
    const int r   = l & 15;        // A row within 16-tile / B col within 16-tile
    const int kg  = l >> 4;        // k-group 0..3 (8 contiguous k each)
    const int rb0 = blockIdx.x * 128 + wid * 32;   // wave's first row

    f32x4 acc[2][4];
#pragma unroll
    for (int i = 0; i < 2; i++)
#pragma unroll
        for (int j = 0; j < 4; j++) acc[i][j] = (f32x4){0.f, 0.f, 0.f, 0.f};

    int row0 = rb0 + r;
    int row1 = rb0 + 16 + r;
    int row0c = row0 < NN ? row0 : NN - 1;   // clamp loads; stores are guarded
    int row1c = row1 < NN ? row1 : NN - 1;
    const float* a0p = x + (size_t)row0c * FIN + kg * 8;
    const float* a1p = x + (size_t)row1c * FIN + kg * 8;

#pragma unroll
    for (int ks = 0; ks < 8; ks++) {
        // B fragments for 4 col-tiles: col = ct*16 + r, k in [ks*32 + kg*8, +8)
        short8 bhi[4], blo[4];
#pragma unroll
        for (int ct = 0; ct < 4; ct++) {
            size_t off = (size_t)(ct * 16 + r) * FIN + ks * 32 + kg * 8;
            bhi[ct] = *(const short8*)(w1hi + off);
            blo[ct] = *(const short8*)(w1lo + off);
        }
        // A: 8 contiguous f32 per row-tile
        float4 af0a = *(const float4*)(a0p + ks * 32);
        float4 af0b = *(const float4*)(a0p + ks * 32 + 4);
        float4 af1a = *(const float4*)(a1p + ks * 32);
        float4 af1b = *(const float4*)(a1p + ks * 32 + 4);
        float a0v[8] = {af0a.x, af0a.y, af0a.z, af0a.w, af0b.x, af0b.y, af0b.z, af0b.w};
        float a1v[8] = {af1a.x, af1a.y, af1a.z, af1a.w, af1b.x, af1b.y, af1b.z, af1b.w};
        short8 ahi0, alo0, ahi1, alo1;
#pragma unroll
        for (int j = 0; j < 8; j++) {
            unsigned short h0 = f2bf_rne(a0v[j]);
            ahi0[j] = (short)h0;
            alo0[j] = (short)f2bf_rne(a0v[j] - bf2f(h0));
            unsigned short h1 = f2bf_rne(a1v[j]);
            ahi1[j] = (short)h1;
            alo1[j] = (short)f2bf_rne(a1v[j] - bf2f(h1));
        }
#pragma unroll
        for (int ct = 0; ct < 4; ct++) {
            acc[0][ct] = __builtin_amdgcn_mfma_f32_16x16x32_bf16(ahi0, bhi[ct], acc[0][ct], 0, 0, 0);
            acc[0][ct] = __builtin_amdgcn_mfma_f32_16x16x32_bf16(ahi0, blo[ct], acc[0][ct], 0, 0, 0);
            acc[0][ct] = __builtin_amdgcn_mfma_f32_16x16x32_bf16(alo0, bhi[ct], acc[0][ct], 0, 0, 0);
            acc[1][ct] = __builtin_amdgcn_mfma_f32_16x16x32_bf16(ahi1, bhi[ct], acc[1][ct], 0, 0, 0);
            acc[1][ct] = __builtin_amdgcn_mfma_f32_16x16x32_bf16(ahi1, blo[ct], acc[1][ct], 0, 0, 0);
            acc[1][ct] = __builtin_amdgcn_mfma_f32_16x16x32_bf16(alo1, bhi[ct], acc[1][ct], 0, 0, 0);
        }
    }
    // C/D layout: col = lane&15, row = (lane>>4)*4 + reg
#pragma unroll
    for (int rt = 0; rt < 2; rt++) {
#pragma unroll
        for (int i = 0; i < 4; i++) {
            int grow = rb0 + rt * 16 + kg * 4 + i;
            if (grow < NN) {
                unsigned short* dst = (unsigned short*)xw + (size_t)grow * HID + r;
#pragma unroll
                for (int ct = 0; ct < 4; ct++)
                    dst[ct * 16] = f2bf_rne(acc[rt][ct][i]);
            }
        }
    }
}

// ---- gather1: predicated uniform batches; NO serial tail ----
// Lanes 0-31: even edges, 32-63: odd edges; lane loads one dword (2 bf16) of row.
// Out-of-range slots clamp the edge index to t-1 and zero the weight.
__global__ __launch_bounds__(256) void gather1_kernel(const int* __restrict__ basev,
                                                      const int* __restrict__ endv,
                                                      const ull* __restrict__ eme,
                                                      const unsigned* __restrict__ xw32,
                                                      const float* __restrict__ dis,
                                                      const float* __restrict__ b,
                                                      float* __restrict__ h) {
    int n = blockIdx.x * 4 + (threadIdx.x >> 6);
    if (n >= NN) return;
    int lane = threadIdx.x & 63;
    int half = lane >> 5;          // 0: even edges, 1: odd edges
    int fl = lane & 31;            // feature-pair index (features 2fl, 2fl+1)
    int s = basev[n], t = endv[n];
    int deg = t - s;
    float acc0 = 0.f, acc1 = 0.f;
    int nbt = (deg + 15) >> 4;     // wave-uniform batch count
    for (int bi = 0; bi < nbt; bi++) {
        int p0 = s + bi * 16 + half;
        ull q[8];
#pragma unroll
        for (int j = 0; j < 8; j++) {
            int idx = p0 + 2 * j;
            int c = idx < t ? idx : (t - 1);
            q[j] = __builtin_nontemporal_load(&eme[c]);
        }
        unsigned u[8];
        float wv[8];
#pragma unroll
        for (int j = 0; j < 8; j++) {
            unsigned src = (unsigned)q[j] & 0x1FFFFu;
            u[j] = xw32[(src << 5) | fl];
            wv[j] = (p0 + 2 * j < t) ? __int_as_float((int)(q[j] >> 32)) : 0.f;
        }
#pragma unroll
        for (int j = 0; j < 8; j++) {
            acc0 += wv[j] * __uint_as_float(u[j] << 16);
            acc1 += wv[j] * __uint_as_float(u[j] & 0xFFFF0000u);
        }
    }
    acc0 += __shfl_xor(acc0, 32);
    acc1 += __shfl_xor(acc1, 32);
    float d = dis[n];
    unsigned un = xw32[((unsigned)n << 5) | fl];
    float2 bv = *(const float2*)(b + 2 * fl);
    float v0 = acc0 + d * d * __uint_as_float(un << 16) + bv.x;
    float v1 = acc1 + d * d * __uint_as_float(un & 0xFFFF0000u) + bv.y;
    if (lane < 32) {
        *(float2*)(h + (size_t)n * HID + 2 * fl) = make_float2(fmaxf(v0, 0.f), fmaxf(v1, 0.f));
    }
}

// ---- GEMM2: hw2[N,64-padded](bf16) = h[N,64] @ W2[64,40]; rows padded to one 128B line ----
__global__ __launch_bounds__(256) void gemm2_kernel(const float* __restrict__ h,
                                                    const float* __restrict__ W,
                                                    __hip_bfloat16* __restrict__ hw) {
    __shared__ float hs[64][65];
    __shared__ float Ws[HID * NC];
    const int tid = threadIdx.x;
    const int base = blockIdx.x * 64;
    for (int v = tid; v < 1024; v += 256) {
        int r = v >> 4, q = v & 15;
        int gr = base + r;
        float4 hv = make_float4(0.f, 0.f, 0.f, 0.f);
        if (gr < NN) hv = *(const float4*)(h + (size_t)gr * HID + q * 4);
        hs[r][q * 4 + 0] = hv.x; hs[r][q * 4 + 1] = hv.y;
        hs[r][q * 4 + 2] = hv.z; hs[r][q * 4 + 3] = hv.w;
    }
    for (int v = tid; v < HID * NC; v += 256) Ws[v] = W[v];
    __syncthreads();
    const int tx = tid & 7;
    const int ty = tid >> 3;
    float acc[2][5] = {};
#pragma unroll 8
    for (int k = 0; k < HID; k++) {
        float h0 = hs[ty * 2 + 0][k];
        float h1 = hs[ty * 2 + 1][k];
        const float* wr = &Ws[k * NC + tx * 5];
        float w0 = wr[0], w1 = wr[1], w2 = wr[2], w3 = wr[3], w4 = wr[4];
        acc[0][0] += h0 * w0; acc[0][1] += h0 * w1; acc[0][2] += h0 * w2;
        acc[0][3] += h0 * w3; acc[0][4] += h0 * w4;
        acc[1][0] += h1 * w0; acc[1][1] += h1 * w1; acc[1][2] += h1 * w2;
        acc[1][3] += h1 * w3; acc[1][4] += h1 * w4;
    }
#pragma unroll
    for (int i = 0; i < 2; i++) {
        int gr = base + ty * 2 + i;
        if (gr < NN) {
#pragma unroll
            for (int c = 0; c < 5; c++)
                hw[(size_t)gr * 64 + tx * 5 + c] = __float2bfloat16(acc[i][c]);
        }
    }
}

// ---- gather2 + final: predicated uniform batches; log_softmax fused ----
__global__ __launch_bounds__(256) void gather2_kernel(const int* __restrict__ basev,
                                                      const int* __restrict__ endv,
                                                      const ull* __restrict__ eme,
                                                      const unsigned* __restrict__ hw32,
                                                      const float* __restrict__ dis,
                                                      const float* __restrict__ b,
                                                      float* __restrict__ out) {
    int n = blockIdx.x * 4 + (threadIdx.x >> 6);
    if (n >= NN) return;
    int lane = threadIdx.x & 63;
    int half = lane >> 5;
    int fl = lane & 31;
    bool act = fl < 20;            // classes 2fl, 2fl+1 < 40
    int s = basev[n], t = endv[n];
    int deg = t - s;
    float acc0 = 0.f, acc1 = 0.f;
    int nbt = (deg + 15) >> 4;     // wave-uniform batch count
    for (int bi = 0; bi < nbt; bi++) {
        int p0 = s + bi * 16 + half;
        ull q[8];
#pragma unroll
        for (int j = 0; j < 8; j++) {
            int idx = p0 + 2 * j;
            int c = idx < t ? idx : (t - 1);
            q[j] = __builtin_nontemporal_load(&eme[c]);
        }
        unsigned u[8];
        float wv[8];
#pragma unroll
        for (int j = 0; j < 8; j++) {
            unsigned src = (unsigned)q[j] & 0x1FFFFu;
            u[j] = hw32[(src << 5) | fl];
            wv[j] = (p0 + 2 * j < t) ? __int_as_float((int)(q[j] >> 32)) : 0.f;
        }
#pragma unroll
        for (int j = 0; j < 8; j++) {
            acc0 += wv[j] * __uint_as_float(u[j] << 16);
            acc1 += wv[j] * __uint_as_float(u[j] & 0xFFFF0000u);
        }
    }
    acc0 += __shfl_xor(acc0, 32);
    acc1 += __shfl_xor(acc1, 32);
    float v0 = 0.f, v1 = 0.f, m = -INFINITY;
    if (act) {
        float d = dis[n];
        unsigned un = hw32[((unsigned)n << 5) | fl];
        float2 bv = *(const float2*)(b + 2 * fl);
        v0 = acc0 + d * d * __uint_as_float(un << 16) + bv.x;
        v1 = acc1 + d * d * __uint_as_float(un & 0xFFFF0000u) + bv.y;
        m = fmaxf(v0, v1);
    }
#pragma unroll
    for (int off = 16; off; off >>= 1) m = fmaxf(m, __shfl_xor(m, off));
    float e0 = act ? expf(v0 - m) : 0.f;
    float e1 = act ? expf(v1 - m) : 0.f;
    float sum = e0 + e1;
#pragma unroll
    for (int off = 16; off; off >>= 1) sum += __shfl_xor(sum, off);
    float lse = m + logf(sum);
    if (act && lane < 32) {
        size_t idx = (size_t)n * NC + 2 * fl;
        *(float2*)(out + idx) = make_float2(v0, v1);
        *(float2*)(out + (size_t)NN * NC + idx) = make_float2(v0 - lse, v1 - lse);
    }
}

extern "C" void kernel_launch(void* const* d_in, const int* in_sizes, int n_in,
                              void* d_out, int out_size, void* d_ws, size_t ws_size,
                              hipStream_t stream) {
    const float* x    = (const float*)d_in[0];
    const int*   eidx = (const int*)d_in[1];
    const float* ew   = (const float*)d_in[2];
    const float* W1   = (const float*)d_in[3];
    const float* b1   = (const float*)d_in[4];
    const float* W2   = (const float*)d_in[5];
    const float* b2   = (const float*)d_in[6];
    float* out = (float*)d_out;

    const int* row = eidx;
    const int* col = eidx + EE;

    char* ws = (char*)d_ws;
    int*   bucket_cnt  = (int*)ws;               ws += 256 * 4;
    int*   bucket_base = (int*)ws;               ws += 256 * 4;
    float* dis    = (float*)ws;                  ws += NN * 4;
    int*   basev  = (int*)ws;                    ws += NN * 4;
    int*   endv   = (int*)ws;                    ws += NN * 4;
    int2*  eme    = (int2*)ws;                   ws += (size_t)EE * 8;
    __hip_bfloat16* xw = (__hip_bfloat16*)ws;    ws += (size_t)NN * HID * 2;
    // staging (16.06 MB) and h (25.6 MB) are never live simultaneously: union them
    char* unionp = ws;                           ws += (size_t)NN * HID * 4;
    int2*  staging = (int2*)unionp;              // NB*BCAP*8 = 16.06 MB <= 25.6 MB
    float* h       = (float*)unionp;
    __hip_bfloat16* hw2 = (__hip_bfloat16*)ws;   ws += (size_t)NN * 64 * 2;  // stride-64 padded
    unsigned short* w1hi = (unsigned short*)ws;  ws += (size_t)HID * FIN * 2; // B^T bf16 hi
    unsigned short* w1lo = (unsigned short*)ws;  ws += (size_t)HID * FIN * 2; // B^T bf16 lo

    hipMemsetAsync(bucket_cnt, 0, 256 * 4, stream);

    bucket_kernel<<<NBKB, 256, 0, stream>>>(row, col, ew, bucket_cnt, staging);
    bscan_w1cvt_kernel<<<5, 256, 0, stream>>>(bucket_cnt, bucket_base, W1, w1hi, w1lo);
    build_count_kernel<<<NB, 512, 0, stream>>>(staging, bucket_cnt, bucket_base,
                                               basev, endv, dis);
    build_place_kernel<<<NB, 512, 0, stream>>>(staging, bucket_cnt, basev, dis, eme);
    gemm1_mfma_kernel<<<(NN + 127) / 128, 256, 0, stream>>>(x, w1hi, w1lo, xw);
    gather1_kernel<<<(NN + 3) / 4, 256, 0, stream>>>(basev, endv, (const ull*)eme,
                                                     (const unsigned*)xw, dis, b1, h);
    gemm2_kernel<<<(NN + 63) / 64, 256, 0, stream>>>(h, W2, hw2);
    gather2_kernel<<<(NN + 3) / 4, 256, 0, stream>>>(basev, endv, (const ull*)eme,
                                                     (const unsigned*)hw2, dis, b2, out);
}

// Round 7
// 370.547 us; speedup vs baseline: 1.3795x; 1.1117x over previous
//
#include <hip/hip_runtime.h>
#include <hip/hip_bf16.h>
#include <math.h>

#define NN 100000
#define EE 1600000
#define FIN 256
#define HID 64
#define NC 40
#define NB 196        // destination buckets of 512 nodes (196*512 = 100352)
#define BCAP 10240    // staging capacity per bucket (mean 8192, +22 sigma)
#define CHUNK 2048    // edges per bucket_kernel block
#define NBKB ((EE + CHUNK - 1) / CHUNK)   // 782

typedef unsigned long long ull;
typedef __attribute__((ext_vector_type(2))) unsigned long long ullx2;
typedef __attribute__((ext_vector_type(8))) short short8;
typedef __attribute__((ext_vector_type(4))) float f32x4;

__device__ __forceinline__ unsigned short f2bf_rne(float f) {
    unsigned u = __float_as_uint(f);
    u += 0x7FFFu + ((u >> 16) & 1u);
    return (unsigned short)(u >> 16);
}
__device__ __forceinline__ float bf2f(unsigned short b) {
    return __uint_as_float((unsigned)b << 16);
}

// accumulate one edge: q = (w<<32)|src ; tbl rows are 32 dwords (64 bf16)
__device__ __forceinline__ void edge_acc(ull q, const unsigned* __restrict__ tbl,
                                         int fl, float& a0, float& a1) {
    unsigned src = (unsigned)q & 0x1FFFFu;
    unsigned u = tbl[(src << 5) | fl];
    float w = __int_as_float((int)(q >> 32));
    a0 += w * __uint_as_float(u << 16);
    a1 += w * __uint_as_float(u & 0xFFFF0000u);
}

// ---- stage edges into destination buckets; LDS-reorder by bucket for coalesced writes ----
__global__ __launch_bounds__(256) void bucket_kernel(const int* __restrict__ row,
                                                     const int* __restrict__ col,
                                                     const float* __restrict__ w,
                                                     int* __restrict__ bucket_cnt,
                                                     int2* __restrict__ staging) {
    __shared__ int2 spay[CHUNK];            // 16 KB  original-order payload
    __shared__ int2 sorted[CHUNK];          // 16 KB  bucket-ordered payload
    __shared__ unsigned char sb[CHUNK];     // 2 KB   bucket id per original slot
    __shared__ unsigned char sbk[CHUNK];    // 2 KB   bucket id per sorted slot
    __shared__ int lcnt[NB], lofs[NB], lstart[NB];
    __shared__ int sscan[256];
    const int tid = threadIdx.x;
    const int e0 = blockIdx.x * CHUNK;
    const int nE = min(CHUNK, EE - e0);
    for (int i = tid; i < nE; i += 256) {
        int e = e0 + i;
        int c = col[e];
        sb[i] = (unsigned char)(c >> 9);
        spay[i] = make_int2(((c & 511) << 17) | row[e], __float_as_int(w[e]));
    }
    for (int i = tid; i < NB; i += 256) lcnt[i] = 0;
    __syncthreads();
    for (int i = tid; i < nE; i += 256) atomicAdd(&lcnt[sb[i]], 1);
    __syncthreads();
    // exclusive scan of lcnt over NB (<=256)
    int v = (tid < NB) ? lcnt[tid] : 0;
    sscan[tid] = v;
    __syncthreads();
    for (int off = 1; off < 256; off <<= 1) {
        int u = (tid >= off) ? sscan[tid - off] : 0;
        __syncthreads();
        sscan[tid] += u;
        __syncthreads();
    }
    if (tid < NB) {
        lofs[tid] = sscan[tid] - v;                       // local exclusive prefix
        lstart[tid] = v ? atomicAdd(&bucket_cnt[tid], v) : 0;  // global base for this block's run
        lcnt[tid] = 0;
    }
    __syncthreads();
    // reorder into bucket-contiguous LDS
    for (int i = tid; i < nE; i += 256) {
        int b = sb[i];
        int p = lofs[b] + atomicAdd(&lcnt[b], 1);
        sorted[p] = spay[i];
        sbk[p] = (unsigned char)b;
    }
    __syncthreads();
    // write out: consecutive threads -> consecutive slots of the same bucket
    for (int p = tid; p < nE; p += 256) {
        int b = sbk[p];
        int slot = lstart[b] + (p - lofs[b]);
        if (slot < BCAP) staging[(size_t)b * BCAP + slot] = sorted[p];
    }
}

// ---- build pass A: per-dest count+degree; within-bucket scan of PADDED degrees ----
// basev <- within-bucket padded offset (fixed up in pass B); endv <- actual count
__global__ __launch_bounds__(512) void build_count_kernel(const int2* __restrict__ staging,
                                                          const int* __restrict__ bucket_cnt,
                                                          int* __restrict__ basev,
                                                          int* __restrict__ endv,
                                                          float* __restrict__ dis,
                                                          int* __restrict__ ptot) {
    __shared__ int dcnt[512];
    __shared__ float dsum[512];
    __shared__ int sscan[512];
    const int t = threadIdx.x;
    const int b = blockIdx.x;
    const int nE = min(bucket_cnt[b], BCAP);
    const int2* st = staging + (size_t)b * BCAP;
    dcnt[t] = 0; dsum[t] = 0.f;
    __syncthreads();
    for (int i = t; i < nE; i += 512) {
        int2 p = st[i];
        int d = p.x >> 17;
        atomicAdd(&dcnt[d], 1);
        atomicAdd(&dsum[d], __int_as_float(p.y));
    }
    __syncthreads();
    int c = dcnt[t];
    int pdeg = (c + 7) & ~7;       // pad each node's range to multiple of 8
    sscan[t] = pdeg;
    __syncthreads();
    for (int off = 1; off < 512; off <<= 1) {
        int u = (t >= off) ? sscan[t - off] : 0;
        __syncthreads();
        sscan[t] += u;
        __syncthreads();
    }
    int gd = b * 512 + t;
    if (gd < NN) {
        basev[gd] = sscan[t] - pdeg;   // within-bucket padded exclusive prefix
        endv[gd] = c;                  // actual count (temporarily)
        dis[gd] = rsqrtf(dsum[t] + 1.0f);   // self-loop weight 1
    }
    if (t == 511) ptot[b] = sscan[511];    // bucket padded total
}

// ---- block 0: exclusive scan of bucket padded totals; blocks 1..4: W1 -> B^T bf16 hi/lo ----
__global__ __launch_bounds__(256) void bscan_w1cvt_kernel(const int* __restrict__ ptot,
                                                          int* __restrict__ bucket_base,
                                                          const float* __restrict__ W1,
                                                          unsigned short* __restrict__ w1hi,
                                                          unsigned short* __restrict__ w1lo) {
    if (blockIdx.x == 0) {
        __shared__ int sd[256];
        int t = threadIdx.x;
        int v = (t < NB) ? ptot[t] : 0;
        sd[t] = v;
        __syncthreads();
        for (int off = 1; off < 256; off <<= 1) {
            int u = (t >= off) ? sd[t - off] : 0;
            __syncthreads();
            sd[t] += u;
            __syncthreads();
        }
        if (t < NB) bucket_base[t] = sd[t] - v;
    } else {
        int b = blockIdx.x - 1;          // 0..3
        for (int i = threadIdx.x; i < 4096; i += 256) {
            int e = b * 4096 + i;        // e = c*256 + k  (B^T layout)
            int c = e >> 8, k = e & 255;
            float v = W1[(size_t)k * HID + c];
            unsigned short h = f2bf_rne(v);
            w1hi[e] = h;
            w1lo[e] = f2bf_rne(v - bf2f(h));
        }
    }
}

// ---- build pass B: fix up global bases, place normalized edges, zero-fill pads ----
__global__ __launch_bounds__(512) void build_place_kernel(const int2* __restrict__ staging,
                                                          const int* __restrict__ bucket_cnt,
                                                          const int* __restrict__ bucket_base,
                                                          int* __restrict__ basev,
                                                          int* __restrict__ endv,
                                                          const float* __restrict__ dis,
                                                          int2* __restrict__ eme) {
    __shared__ int dcur[512];
    __shared__ float sdis[512];
    const int t = threadIdx.x;
    const int b = blockIdx.x;
    const int nE = min(bucket_cnt[b], BCAP);
    const int2* st = staging + (size_t)b * BCAP;
    const int gd = b * 512 + t;
    int gb = 0, c = 0, pdeg = 0;
    if (gd < NN) {
        gb = bucket_base[b] + basev[gd];
        c = endv[gd];
        pdeg = (c + 7) & ~7;
        basev[gd] = gb;
        endv[gd] = gb + c;
        sdis[t] = dis[gd];
    } else {
        sdis[t] = 0.f;
    }
    dcur[t] = gb;
    __syncthreads();
    for (int i = t; i < nE; i += 512) {
        int2 p = st[i];
        int d = p.x >> 17;
        int src = p.x & 0x1FFFF;
        int pos = atomicAdd(&dcur[d], 1);
        float wn = __int_as_float(p.y) * dis[src] * sdis[d];
        eme[pos] = make_int2(src, __float_as_int(wn));
    }
    // zero-weight pads: src=0 (valid row) x 0 weight
    for (int i = c; i < pdeg; i++) eme[gb + i] = make_int2(0, 0);
}

// ---- GEMM1 (MFMA, split-bf16 f32 emulation): xw[N,64](bf16) = x[N,256] @ W1[256,64] ----
__global__ __launch_bounds__(256) void gemm1_mfma_kernel(const float* __restrict__ x,
                                                         const unsigned short* __restrict__ w1hi,
                                                         const unsigned short* __restrict__ w1lo,
                                                         __hip_bfloat16* __restrict__ xw) {
    const int tid = threadIdx.x;
    const int wid = tid >> 6;
    const int l   = tid & 63;
    const int r   = l & 15;        // A row within 16-tile / B col within 16-tile
    const int kg  = l >> 4;        // k-group 0..3 (8 contiguous k each)
    const int rb0 = blockIdx.x * 128 + wid * 32;   // wave's first row

    f32x4 acc[2][4];
#pragma unroll
    for (int i = 0; i < 2; i++)
#pragma unroll
        for (int j = 0; j < 4; j++) acc[i][j] = (f32x4){0.f, 0.f, 0.f, 0.f};

    int row0 = rb0 + r;
    int row1 = rb0 + 16 + r;
    int row0c = row0 < NN ? row0 : NN - 1;   // clamp loads; stores are guarded
    int row1c = row1 < NN ? row1 : NN - 1;
    const float* a0p = x + (size_t)row0c * FIN + kg * 8;
    const float* a1p = x + (size_t)row1c * FIN + kg * 8;

#pragma unroll
    for (int ks = 0; ks < 8; ks++) {
        // B fragments for 4 col-tiles: col = ct*16 + r, k in [ks*32 + kg*8, +8)
        short8 bhi[4], blo[4];
#pragma unroll
        for (int ct = 0; ct < 4; ct++) {
            size_t off = (size_t)(ct * 16 + r) * FIN + ks * 32 + kg * 8;
            bhi[ct] = *(const short8*)(w1hi + off);
            blo[ct] = *(const short8*)(w1lo + off);
        }
        // A: 8 contiguous f32 per row-tile
        float4 af0a = *(const float4*)(a0p + ks * 32);
        float4 af0b = *(const float4*)(a0p + ks * 32 + 4);
        float4 af1a = *(const float4*)(a1p + ks * 32);
        float4 af1b = *(const float4*)(a1p + ks * 32 + 4);
        float a0v[8] = {af0a.x, af0a.y, af0a.z, af0a.w, af0b.x, af0b.y, af0b.z, af0b.w};
        float a1v[8] = {af1a.x, af1a.y, af1a.z, af1a.w, af1b.x, af1b.y, af1b.z, af1b.w};
        short8 ahi0, alo0, ahi1, alo1;
#pragma unroll
        for (int j = 0; j < 8; j++) {
            unsigned short h0 = f2bf_rne(a0v[j]);
            ahi0[j] = (short)h0;
            alo0[j] = (short)f2bf_rne(a0v[j] - bf2f(h0));
            unsigned short h1 = f2bf_rne(a1v[j]);
            ahi1[j] = (short)h1;
            alo1[j] = (short)f2bf_rne(a1v[j] - bf2f(h1));
        }
#pragma unroll
        for (int ct = 0; ct < 4; ct++) {
            acc[0][ct] = __builtin_amdgcn_mfma_f32_16x16x32_bf16(ahi0, bhi[ct], acc[0][ct], 0, 0, 0);
            acc[0][ct] = __builtin_amdgcn_mfma_f32_16x16x32_bf16(ahi0, blo[ct], acc[0][ct], 0, 0, 0);
            acc[0][ct] = __builtin_amdgcn_mfma_f32_16x16x32_bf16(alo0, bhi[ct], acc[0][ct], 0, 0, 0);
            acc[1][ct] = __builtin_amdgcn_mfma_f32_16x16x32_bf16(ahi1, bhi[ct], acc[1][ct], 0, 0, 0);
            acc[1][ct] = __builtin_amdgcn_mfma_f32_16x16x32_bf16(ahi1, blo[ct], acc[1][ct], 0, 0, 0);
            acc[1][ct] = __builtin_amdgcn_mfma_f32_16x16x32_bf16(alo1, bhi[ct], acc[1][ct], 0, 0, 0);
        }
    }
    // C/D layout: col = lane&15, row = (lane>>4)*4 + reg
#pragma unroll
    for (int rt = 0; rt < 2; rt++) {
#pragma unroll
        for (int i = 0; i < 4; i++) {
            int grow = rb0 + rt * 16 + kg * 4 + i;
            if (grow < NN) {
                unsigned short* dst = (unsigned short*)xw + (size_t)grow * HID + r;
#pragma unroll
                for (int ct = 0; ct < 4; ct++)
                    dst[ct * 16] = f2bf_rne(acc[rt][ct][i]);
            }
        }
    }
}

// ---- gather1: padded ranges -> zero predication, contiguous 16B loads ----
// Half h of the wave takes the h-th contiguous 8-edge sub-block of each 16-batch.
__global__ __launch_bounds__(256) void gather1_kernel(const int* __restrict__ basev,
                                                      const int* __restrict__ endv,
                                                      const ull* __restrict__ eme,
                                                      const unsigned* __restrict__ xw32,
                                                      const float* __restrict__ dis,
                                                      const float* __restrict__ b,
                                                      float* __restrict__ h) {
    int n = blockIdx.x * 4 + (threadIdx.x >> 6);
    if (n >= NN) return;
    int lane = threadIdx.x & 63;
    int half = lane >> 5;
    int fl = lane & 31;            // feature-pair index (features 2fl, 2fl+1)
    int s = basev[n], t = endv[n];
    int pdeg = (t - s + 7) & ~7;   // padded range length (pads are zero-weight)
    float acc0 = 0.f, acc1 = 0.f;
    int nb16 = pdeg >> 4;
    for (int bi = 0; bi < nb16; bi++) {
        const ull* pp = eme + s + bi * 16 + 8 * half;   // 16B-aligned by construction
        ullx2 qa = *(const ullx2*)(pp);
        ullx2 qb = *(const ullx2*)(pp + 2);
        ullx2 qc = *(const ullx2*)(pp + 4);
        ullx2 qd = *(const ullx2*)(pp + 6);
        edge_acc(qa[0], xw32, fl, acc0, acc1);
        edge_acc(qa[1], xw32, fl, acc0, acc1);
        edge_acc(qb[0], xw32, fl, acc0, acc1);
        edge_acc(qb[1], xw32, fl, acc0, acc1);
        edge_acc(qc[0], xw32, fl, acc0, acc1);
        edge_acc(qc[1], xw32, fl, acc0, acc1);
        edge_acc(qd[0], xw32, fl, acc0, acc1);
        edge_acc(qd[1], xw32, fl, acc0, acc1);
    }
    if (pdeg & 8) {                 // one 8-edge batch, 4 edges per half
        const ull* pp = eme + s + nb16 * 16 + 4 * half;
        ullx2 qa = *(const ullx2*)(pp);
        ullx2 qb = *(const ullx2*)(pp + 2);
        edge_acc(qa[0], xw32, fl, acc0, acc1);
        edge_acc(qa[1], xw32, fl, acc0, acc1);
        edge_acc(qb[0], xw32, fl, acc0, acc1);
        edge_acc(qb[1], xw32, fl, acc0, acc1);
    }
    acc0 += __shfl_xor(acc0, 32);
    acc1 += __shfl_xor(acc1, 32);
    float d = dis[n];
    unsigned un = xw32[((unsigned)n << 5) | fl];
    float2 bv = *(const float2*)(b + 2 * fl);
    float v0 = acc0 + d * d * __uint_as_float(un << 16) + bv.x;
    float v1 = acc1 + d * d * __uint_as_float(un & 0xFFFF0000u) + bv.y;
    if (lane < 32) {
        *(float2*)(h + (size_t)n * HID + 2 * fl) = make_float2(fmaxf(v0, 0.f), fmaxf(v1, 0.f));
    }
}

// ---- GEMM2: hw2[N,64-padded](bf16) = h[N,64] @ W2[64,40]; rows padded to one 128B line ----
__global__ __launch_bounds__(256) void gemm2_kernel(const float* __restrict__ h,
                                                    const float* __restrict__ W,
                                                    __hip_bfloat16* __restrict__ hw) {
    __shared__ float hs[64][65];
    __shared__ float Ws[HID * NC];
    const int tid = threadIdx.x;
    const int base = blockIdx.x * 64;
    for (int v = tid; v < 1024; v += 256) {
        int r = v >> 4, q = v & 15;
        int gr = base + r;
        float4 hv = make_float4(0.f, 0.f, 0.f, 0.f);
        if (gr < NN) hv = *(const float4*)(h + (size_t)gr * HID + q * 4);
        hs[r][q * 4 + 0] = hv.x; hs[r][q * 4 + 1] = hv.y;
        hs[r][q * 4 + 2] = hv.z; hs[r][q * 4 + 3] = hv.w;
    }
    for (int v = tid; v < HID * NC; v += 256) Ws[v] = W[v];
    __syncthreads();
    const int tx = tid & 7;
    const int ty = tid >> 3;
    float acc[2][5] = {};
#pragma unroll 8
    for (int k = 0; k < HID; k++) {
        float h0 = hs[ty * 2 + 0][k];
        float h1 = hs[ty * 2 + 1][k];
        const float* wr = &Ws[k * NC + tx * 5];
        float w0 = wr[0], w1 = wr[1], w2 = wr[2], w3 = wr[3], w4 = wr[4];
        acc[0][0] += h0 * w0; acc[0][1] += h0 * w1; acc[0][2] += h0 * w2;
        acc[0][3] += h0 * w3; acc[0][4] += h0 * w4;
        acc[1][0] += h1 * w0; acc[1][1] += h1 * w1; acc[1][2] += h1 * w2;
        acc[1][3] += h1 * w3; acc[1][4] += h1 * w4;
    }
#pragma unroll
    for (int i = 0; i < 2; i++) {
        int gr = base + ty * 2 + i;
        if (gr < NN) {
#pragma unroll
            for (int c = 0; c < 5; c++)
                hw[(size_t)gr * 64 + tx * 5 + c] = __float2bfloat16(acc[i][c]);
        }
    }
}

// ---- gather2 + final: padded ranges, zero predication; log_softmax fused ----
__global__ __launch_bounds__(256) void gather2_kernel(const int* __restrict__ basev,
                                                      const int* __restrict__ endv,
                                                      const ull* __restrict__ eme,
                                                      const unsigned* __restrict__ hw32,
                                                      const float* __restrict__ dis,
                                                      const float* __restrict__ b,
                                                      float* __restrict__ out) {
    int n = blockIdx.x * 4 + (threadIdx.x >> 6);
    if (n >= NN) return;
    int lane = threadIdx.x & 63;
    int half = lane >> 5;
    int fl = lane & 31;
    bool act = fl < 20;            // classes 2fl, 2fl+1 < 40
    int s = basev[n], t = endv[n];
    int pdeg = (t - s + 7) & ~7;
    float acc0 = 0.f, acc1 = 0.f;
    int nb16 = pdeg >> 4;
    for (int bi = 0; bi < nb16; bi++) {
        const ull* pp = eme + s + bi * 16 + 8 * half;
        ullx2 qa = *(const ullx2*)(pp);
        ullx2 qb = *(const ullx2*)(pp + 2);
        ullx2 qc = *(const ullx2*)(pp + 4);
        ullx2 qd = *(const ullx2*)(pp + 6);
        edge_acc(qa[0], hw32, fl, acc0, acc1);
        edge_acc(qa[1], hw32, fl, acc0, acc1);
        edge_acc(qb[0], hw32, fl, acc0, acc1);
        edge_acc(qb[1], hw32, fl, acc0, acc1);
        edge_acc(qc[0], hw32, fl, acc0, acc1);
        edge_acc(qc[1], hw32, fl, acc0, acc1);
        edge_acc(qd[0], hw32, fl, acc0, acc1);
        edge_acc(qd[1], hw32, fl, acc0, acc1);
    }
    if (pdeg & 8) {
        const ull* pp = eme + s + nb16 * 16 + 4 * half;
        ullx2 qa = *(const ullx2*)(pp);
        ullx2 qb = *(const ullx2*)(pp + 2);
        edge_acc(qa[0], hw32, fl, acc0, acc1);
        edge_acc(qa[1], hw32, fl, acc0, acc1);
        edge_acc(qb[0], hw32, fl, acc0, acc1);
        edge_acc(qb[1], hw32, fl, acc0, acc1);
    }
    acc0 += __shfl_xor(acc0, 32);
    acc1 += __shfl_xor(acc1, 32);
    float v0 = 0.f, v1 = 0.f, m = -INFINITY;
    if (act) {
        float d = dis[n];
        unsigned un = hw32[((unsigned)n << 5) | fl];
        float2 bv = *(const float2*)(b + 2 * fl);
        v0 = acc0 + d * d * __uint_as_float(un << 16) + bv.x;
        v1 = acc1 + d * d * __uint_as_float(un & 0xFFFF0000u) + bv.y;
        m = fmaxf(v0, v1);
    }
#pragma unroll
    for (int off = 16; off; off >>= 1) m = fmaxf(m, __shfl_xor(m, off));
    float e0 = act ? expf(v0 - m) : 0.f;
    float e1 = act ? expf(v1 - m) : 0.f;
    float sum = e0 + e1;
#pragma unroll
    for (int off = 16; off; off >>= 1) sum += __shfl_xor(sum, off);
    float lse = m + logf(sum);
    if (act && lane < 32) {
        size_t idx = (size_t)n * NC + 2 * fl;
        *(float2*)(out + idx) = make_float2(v0, v1);
        *(float2*)(out + (size_t)NN * NC + idx) = make_float2(v0 - lse, v1 - lse);
    }
}

extern "C" void kernel_launch(void* const* d_in, const int* in_sizes, int n_in,
                              void* d_out, int out_size, void* d_ws, size_t ws_size,
                              hipStream_t stream) {
    const float* x    = (const float*)d_in[0];
    const int*   eidx = (const int*)d_in[1];
    const float* ew   = (const float*)d_in[2];
    const float* W1   = (const float*)d_in[3];
    const float* b1   = (const float*)d_in[4];
    const float* W2   = (const float*)d_in[5];
    const float* b2   = (const float*)d_in[6];
    float* out = (float*)d_out;

    const int* row = eidx;
    const int* col = eidx + EE;

    char* ws = (char*)d_ws;
    int*   bucket_cnt  = (int*)ws;               ws += 256 * 4;
    int*   bucket_base = (int*)ws;               ws += 256 * 4;
    int*   ptot        = (int*)ws;               ws += 256 * 4;
    float* dis    = (float*)ws;                  ws += NN * 4;
    int*   basev  = (int*)ws;                    ws += NN * 4;
    int*   endv   = (int*)ws;                    ws += NN * 4;
    int2*  eme    = (int2*)ws;                   ws += ((size_t)EE + 8 * NN) * 8;  // padded
    __hip_bfloat16* xw = (__hip_bfloat16*)ws;    ws += (size_t)NN * HID * 2;
    // staging (16.06 MB) and h (25.6 MB) are never live simultaneously: union them
    char* unionp = ws;                           ws += (size_t)NN * HID * 4;
    int2*  staging = (int2*)unionp;              // NB*BCAP*8 = 16.06 MB <= 25.6 MB
    float* h       = (float*)unionp;
    __hip_bfloat16* hw2 = (__hip_bfloat16*)ws;   ws += (size_t)NN * 64 * 2;  // stride-64 padded
    unsigned short* w1hi = (unsigned short*)ws;  ws += (size_t)HID * FIN * 2; // B^T bf16 hi
    unsigned short* w1lo = (unsigned short*)ws;  ws += (size_t)HID * FIN * 2; // B^T bf16 lo

    hipMemsetAsync(bucket_cnt, 0, 256 * 4, stream);

    bucket_kernel<<<NBKB, 256, 0, stream>>>(row, col, ew, bucket_cnt, staging);
    build_count_kernel<<<NB, 512, 0, stream>>>(staging, bucket_cnt,
                                               basev, endv, dis, ptot);
    bscan_w1cvt_kernel<<<5, 256, 0, stream>>>(ptot, bucket_base, W1, w1hi, w1lo);
    build_place_kernel<<<NB, 512, 0, stream>>>(staging, bucket_cnt, bucket_base,
                                               basev, endv, dis, eme);
    gemm1_mfma_kernel<<<(NN + 127) / 128, 256, 0, stream>>>(x, w1hi, w1lo, xw);
    gather1_kernel<<<(NN + 3) / 4, 256, 0, stream>>>(basev, endv, (const ull*)eme,
                                                     (const unsigned*)xw, dis, b1, h);
    gemm2_kernel<<<(NN + 63) / 64, 256, 0, stream>>>(h, W2, hw2);
    gather2_kernel<<<(NN + 3) / 4, 256, 0, stream>>>(basev, endv, (const ull*)eme,
                                                     (const unsigned*)hw2, dis, b2, out);
}